// Round 6
// baseline (341.643 us; speedup 1.0000x reference)
//
#include <hip/hip_runtime.h>
#include <hip/hip_bf16.h>

typedef float floatx4 __attribute__((ext_vector_type(4)));
typedef short shortx8 __attribute__((ext_vector_type(8)));
typedef short shortx4 __attribute__((ext_vector_type(4)));

#define CFENCE() asm volatile("" ::: "memory")

__device__ __forceinline__ float bf2f(short s) {
    union { unsigned u; float f; } cv;
    cv.u = ((unsigned)(unsigned short)s) << 16;
    return cv.f;
}
__device__ __forceinline__ short f2bf(float f) {
    union { float f; unsigned u; } cv; cv.f = f;
    unsigned r = (cv.u + 0x7fffu + ((cv.u >> 16) & 1u)) >> 16;
    return (short)r;
}

// ---------------- K0a: weights -> bf16 fragment-major layout ----------------
__global__ __launch_bounds__(256) void wtrans(const float* __restrict__ Wq,
                                              const float* __restrict__ Wk,
                                              const float* __restrict__ Wv,
                                              const float* __restrict__ Wo,
                                              short* __restrict__ wqkv_f,
                                              short* __restrict__ wo_f) {
    int gtid = blockIdx.x * 256 + threadIdx.x;
    int f = gtid >> 6, lane = gtid & 63;
    int quad = lane >> 4, l15 = lane & 15;
    if (f < 384) {
        int n16 = f >> 3, kt = f & 7;
        int n = n16 * 16 + l15, z = n >> 8, ncol = n & 255;
        const float* src = (z == 0) ? Wq : (z == 1) ? Wk : Wv;
        shortx8 s;
#pragma unroll
        for (int j = 0; j < 8; ++j)
            s[j] = f2bf(src[(size_t)(kt * 32 + quad * 8 + j) * 256 + ncol]);
        *(shortx8*)(wqkv_f + (size_t)f * 512 + lane * 8) = s;
    } else {
        int f2 = f - 384;
        int n16 = f2 >> 3, kt = f2 & 7;
        int n = n16 * 16 + l15;
        shortx8 s;
#pragma unroll
        for (int j = 0; j < 8; ++j)
            s[j] = f2bf(Wo[(size_t)(kt * 32 + quad * 8 + j) * 256 + n]);
        *(shortx8*)(wo_f + (size_t)f2 * 512 + lane * 8) = s;
    }
}

// ---------------- K0b: CPB MLP ----------------
__device__ __forceinline__ float sgnlog(float x) {
    return copysignf(__log2f(fabsf(x) + 1.f) / 3.f, x);
}
__global__ __launch_bounds__(256) void bias_mlp(const float* __restrict__ ls,
                                                const float* __restrict__ w1,
                                                const float* __restrict__ b1,
                                                const float* __restrict__ w2,
                                                float* __restrict__ b225g,
                                                float* __restrict__ scaleOut) {
    int e = blockIdx.x;
    int tid = threadIdx.x, lane = tid & 63, wid = tid >> 6;
    if (e == 0 && tid < 8) scaleOut[tid] = expf(fminf(ls[tid], 4.6051701859880914f));
    int dh = e / 15 - 7, dw = e % 15 - 7;
    float t0 = sgnlog(8.f * (float)dh / 7.f);
    float t1 = sgnlog(8.f * (float)dw / 7.f);
    float acc[8];
#pragma unroll
    for (int j = 0; j < 8; ++j) acc[j] = 0.f;
#pragma unroll
    for (int s = 0; s < 2; ++s) {
        int hsm = tid + s * 256;
        float hid = fmaxf(0.f, t0 * w1[hsm] + t1 * w1[512 + hsm] + b1[hsm]);
#pragma unroll
        for (int j = 0; j < 8; ++j) acc[j] += hid * w2[hsm * 8 + j];
    }
#pragma unroll
    for (int off = 1; off < 64; off <<= 1)
#pragma unroll
        for (int j = 0; j < 8; ++j) acc[j] += __shfl_xor(acc[j], off, 64);
    __shared__ float red[4][8];
    if (lane == 0)
#pragma unroll
        for (int j = 0; j < 8; ++j) red[wid][j] = acc[j];
    __syncthreads();
    if (tid < 8)
        b225g[e * 8 + tid] = red[0][tid] + red[1][tid] + red[2][tid] + red[3][tid];
}

// ---------------- K0c: expand to per-head 64x64 bias, TRANSPOSED [h][j][i] ----------------
__global__ __launch_bounds__(256) void bias_expand(const float* __restrict__ b225g,
                                                   float* __restrict__ bias_t) {
    int f = blockIdx.x * 256 + threadIdx.x;
    int h = f >> 12, ij = f & 4095, i = ij >> 6, j = ij & 63;
    int dh = (i >> 3) - (j >> 3), dw = (i & 7) - (j & 7);
    int e = (dh + 7) * 15 + (dw + 7);
    float v = b225g[e * 8 + h];
    bias_t[(h << 12) + j * 64 + i] = 16.f / (1.f + expf(-v));
}

// token row -> pixel (roll by +4 both ways, same map fwd/bwd)
__device__ __forceinline__ int row2pix(int row) {
    int w = row >> 6, t = row & 63;
    int b = w >> 6, wi = (w >> 3) & 7, wj = w & 7;
    int hh = (wi * 8 + (t >> 3) + 4) & 63;
    int ww = (wj * 8 + (t & 7) + 4) & 63;
    return (b * 64 + hh) * 64 + ww;
}

__device__ __forceinline__ int regid(int t, int wi, int wj) {
    int a = (wi < 7) ? 0 : (((t >> 3) < 4) ? 1 : 2);
    int b = (wj < 7) ? 0 : (((t & 7) < 4) ? 1 : 2);
    return a * 3 + b;
}

// ---------------- K0d: x -> bf16 token-fragment layout ----------------
__global__ __launch_bounds__(256) void xtrans(const float* __restrict__ x,
                                              short* __restrict__ xbf) {
    int win = blockIdx.x;
    int tid = threadIdx.x;
    int r = tid >> 2, q = tid & 3;
    const float* src = x + (size_t)row2pix(win * 64 + r) * 256 + q * 64;
    size_t fb = (size_t)(win * 4 + (r >> 4)) * 8;
    int l15r = r & 15;
#pragma unroll
    for (int kt2 = 0; kt2 < 2; ++kt2) {
        int kt = q * 2 + kt2;
        short* dst = xbf + (fb + kt) * 512 + l15r * 8;
#pragma unroll
        for (int quad = 0; quad < 4; ++quad) {
            floatx4 u0 = __builtin_nontemporal_load((const floatx4*)(src + kt2 * 32 + quad * 8));
            floatx4 u1 = __builtin_nontemporal_load((const floatx4*)(src + kt2 * 32 + quad * 8 + 4));
            shortx8 t;
            t[0] = f2bf(u0[0]); t[1] = f2bf(u0[1]); t[2] = f2bf(u0[2]); t[3] = f2bf(u0[3]);
            t[4] = f2bf(u1[0]); t[5] = f2bf(u1[1]); t[6] = f2bf(u1[2]); t[7] = f2bf(u1[3]);
            *(shortx8*)(dst + quad * 128) = t;
        }
    }
}

// ---------------- Fused: QKV + attention + O-proj, one block per window ----------------
// Round-3 structure (single-phase QKV, padded row-major wave-private LDS) with:
//   strides 40->34 (qn/kn, odd bank-step = conflict-free) and 72->68 (vt/P),
//   per-wave 6528 shorts -> block LDS 52224 B -> 3 blocks/CU, launch_bounds(256,3),
//   nontemporal loads of xbf, nontemporal stores of out (kill RFO).
__global__ __launch_bounds__(256, 3) void swin_fused(const short* __restrict__ xbf,
                                                     const short* __restrict__ wf,
                                                     const short* __restrict__ wof,
                                                     const float* __restrict__ bq,
                                                     const float* __restrict__ bk_,
                                                     const float* __restrict__ bv,
                                                     const float* __restrict__ bo,
                                                     const float* __restrict__ bias_t,
                                                     const float* __restrict__ scale,
                                                     float* __restrict__ out) {
    __shared__ __align__(16) short lds[26112];   // 52224 B
    int tid = threadIdx.x, lane = tid & 63, wid = tid >> 6;
    int quad = lane >> 4, l15 = lane & 15;
    int win = blockIdx.x;
    int wi = (win >> 3) & 7, wj = win & 7;
    bool need_mask = (wi == 7) || (wj == 7);

    short* qn = &lds[wid * 6528];   // [64][34]  (2176)
    short* kn = qn + 2176;          // [64][34]  (2176)
    short* vt = qn + 4352;          // [32][68]  (2176)
    short* P  = qn;                 // [64][68]  (4352) aliases qn+kn after frags read

    const short* xfb = xbf + (size_t)(win * 4) * 8 * 512 + lane * 8;

    shortx4 Obf[2][4][2];                // per-pass attn output, bf16-packed

#pragma unroll
    for (int p = 0; p < 2; ++p) {
        int h = wid * 2 + p;
        // ---- QKV GEMM (C^T): 24 MFMA per kt ----
        floatx4 aq[2][4], ak[2][4], av[2][4];
#pragma unroll
        for (int i = 0; i < 2; ++i)
#pragma unroll
            for (int mt = 0; mt < 4; ++mt) {
                aq[i][mt] = (floatx4){0.f, 0.f, 0.f, 0.f};
                ak[i][mt] = (floatx4){0.f, 0.f, 0.f, 0.f};
                av[i][mt] = (floatx4){0.f, 0.f, 0.f, 0.f};
            }
#pragma unroll
        for (int kt = 0; kt < 8; ++kt) {
            shortx8 af[4];
#pragma unroll
            for (int mt = 0; mt < 4; ++mt)
                af[mt] = __builtin_nontemporal_load((const shortx8*)(xfb + (size_t)(mt * 8 + kt) * 512));
            shortx8 wqf[2], wkf[2], wvf[2];
#pragma unroll
            for (int i = 0; i < 2; ++i) {
                int n16 = 2 * h + i;
                wqf[i] = *(const shortx8*)(wf + (size_t)((n16)*8 + kt) * 512 + lane * 8);
                wkf[i] = *(const shortx8*)(wf + (size_t)((16 + n16) * 8 + kt) * 512 + lane * 8);
                wvf[i] = *(const shortx8*)(wf + (size_t)((32 + n16) * 8 + kt) * 512 + lane * 8);
            }
#pragma unroll
            for (int i = 0; i < 2; ++i)
#pragma unroll
                for (int mt = 0; mt < 4; ++mt) {
                    aq[i][mt] = __builtin_amdgcn_mfma_f32_16x16x32_bf16(wqf[i], af[mt], aq[i][mt], 0, 0, 0);
                    ak[i][mt] = __builtin_amdgcn_mfma_f32_16x16x32_bf16(wkf[i], af[mt], ak[i][mt], 0, 0, 0);
                    av[i][mt] = __builtin_amdgcn_mfma_f32_16x16x32_bf16(wvf[i], af[mt], av[i][mt], 0, 0, 0);
                }
        }
        // ---- bias + cosine norms (token = col; sum over quads via shfl) ----
        float sc = scale[h];
        float qs[4], ks[4];
#pragma unroll
        for (int mt = 0; mt < 4; ++mt) { qs[mt] = 0.f; ks[mt] = 0.f; }
#pragma unroll
        for (int i = 0; i < 2; ++i) {
            float bqv[4], bkv[4], bvv[4];
#pragma unroll
            for (int r = 0; r < 4; ++r) {
                int d = i * 16 + quad * 4 + r;
                bqv[r] = bq[h * 32 + d];
                bkv[r] = bk_[h * 32 + d];
                bvv[r] = bv[h * 32 + d];
            }
#pragma unroll
            for (int mt = 0; mt < 4; ++mt)
#pragma unroll
                for (int r = 0; r < 4; ++r) {
                    float qv = aq[i][mt][r] + bqv[r]; aq[i][mt][r] = qv; qs[mt] += qv * qv;
                    float kv = ak[i][mt][r] + bkv[r]; ak[i][mt][r] = kv; ks[mt] += kv * kv;
                    av[i][mt][r] += bvv[r];
                }
        }
#pragma unroll
        for (int mt = 0; mt < 4; ++mt) {
            qs[mt] += __shfl_xor(qs[mt], 16, 64); qs[mt] += __shfl_xor(qs[mt], 32, 64);
            ks[mt] += __shfl_xor(ks[mt], 16, 64); ks[mt] += __shfl_xor(ks[mt], 32, 64);
        }
        CFENCE();
        // ---- write normalized q,k (A-frag rows) and transposed v into LDS ----
#pragma unroll
        for (int mt = 0; mt < 4; ++mt) {
            float qr = sc / fmaxf(sqrtf(qs[mt]), 1e-12f);
            float kr = 1.f / fmaxf(sqrtf(ks[mt]), 1e-12f);
            int tok = mt * 16 + l15;
#pragma unroll
            for (int i = 0; i < 2; ++i) {
                shortx4 oq, ok;
#pragma unroll
                for (int r = 0; r < 4; ++r) {
                    oq[r] = f2bf(aq[i][mt][r] * qr);
                    ok[r] = f2bf(ak[i][mt][r] * kr);
                }
                *(shortx4*)&qn[tok * 34 + i * 16 + quad * 4] = oq;
                *(shortx4*)&kn[tok * 34 + i * 16 + quad * 4] = ok;
#pragma unroll
                for (int r = 0; r < 4; ++r)
                    vt[(i * 16 + quad * 4 + r) * 68 + tok] = f2bf(av[i][mt][r]);
            }
        }
        CFENCE();
        // ---- QK^T ----
        shortx8 aqf[4], bkf[4];
#pragma unroll
        for (int mt = 0; mt < 4; ++mt)
            aqf[mt] = *(const shortx8*)&qn[(mt * 16 + l15) * 34 + quad * 8];
#pragma unroll
        for (int nt = 0; nt < 4; ++nt)
            bkf[nt] = *(const shortx8*)&kn[(nt * 16 + l15) * 34 + quad * 8];
        floatx4 S[4][4];
#pragma unroll
        for (int mt = 0; mt < 4; ++mt)
#pragma unroll
            for (int nt = 0; nt < 4; ++nt) {
                floatx4 z = {0.f, 0.f, 0.f, 0.f};
                S[mt][nt] = __builtin_amdgcn_mfma_f32_16x16x32_bf16(aqf[mt], bkf[nt], z, 0, 0, 0);
            }
        // ---- softmax (bias via transposed float4 loads) ----
        const float* bh = bias_t + (h << 12);
        float bound = sc + 16.5f;
        int jid[4];
        if (need_mask) {
#pragma unroll
            for (int nt = 0; nt < 4; ++nt) jid[nt] = regid(nt * 16 + l15, wi, wj);
        }
        float rs[4][4];
#pragma unroll
        for (int mt = 0; mt < 4; ++mt) {
            float4 b4[4];
#pragma unroll
            for (int nt = 0; nt < 4; ++nt)
                b4[nt] = *(const float4*)&bh[(nt * 16 + l15) * 64 + mt * 16 + quad * 4];
#pragma unroll
            for (int reg = 0; reg < 4; ++reg) {
                int i = mt * 16 + quad * 4 + reg;
                int iid = need_mask ? regid(i, wi, wj) : 0;
                float rowsum = 0.f;
#pragma unroll
                for (int nt = 0; nt < 4; ++nt) {
                    float bb = (reg == 0) ? b4[nt].x : (reg == 1) ? b4[nt].y
                             : (reg == 2) ? b4[nt].z : b4[nt].w;
                    float v = S[mt][nt][reg] + bb;
                    if (need_mask && iid != jid[nt]) v -= 100.f;
                    float pe = __expf(v - bound);
                    S[mt][nt][reg] = pe;
                    rowsum += pe;
                }
                rowsum += __shfl_xor(rowsum, 1, 64);
                rowsum += __shfl_xor(rowsum, 2, 64);
                rowsum += __shfl_xor(rowsum, 4, 64);
                rowsum += __shfl_xor(rowsum, 8, 64);
                rs[mt][reg] = 1.f / rowsum;
            }
        }
        CFENCE();
        // ---- P into LDS (aliases qn+kn; frags already consumed) ----
#pragma unroll
        for (int mt = 0; mt < 4; ++mt)
#pragma unroll
            for (int nt = 0; nt < 4; ++nt)
#pragma unroll
                for (int reg = 0; reg < 4; ++reg)
                    P[(mt * 16 + quad * 4 + reg) * 68 + nt * 16 + l15] = f2bf(S[mt][nt][reg]);
        CFENCE();
        // ---- PV ----
        floatx4 O[4][2];
#pragma unroll
        for (int mt = 0; mt < 4; ++mt)
#pragma unroll
            for (int nt = 0; nt < 2; ++nt) O[mt][nt] = (floatx4){0.f, 0.f, 0.f, 0.f};
#pragma unroll
        for (int ks2 = 0; ks2 < 2; ++ks2) {
            shortx8 pa[4], vb[2];
#pragma unroll
            for (int mt = 0; mt < 4; ++mt)
                pa[mt] = *(const shortx8*)&P[(mt * 16 + l15) * 68 + ks2 * 32 + quad * 8];
#pragma unroll
            for (int nt = 0; nt < 2; ++nt)
                vb[nt] = *(const shortx8*)&vt[(nt * 16 + l15) * 68 + ks2 * 32 + quad * 8];
#pragma unroll
            for (int mt = 0; mt < 4; ++mt)
#pragma unroll
                for (int nt = 0; nt < 2; ++nt)
                    O[mt][nt] = __builtin_amdgcn_mfma_f32_16x16x32_bf16(pa[mt], vb[nt], O[mt][nt], 0, 0, 0);
        }
        // ---- scale + pack to bf16 immediately ----
#pragma unroll
        for (int mt = 0; mt < 4; ++mt)
#pragma unroll
            for (int nt = 0; nt < 2; ++nt) {
                shortx4 s;
#pragma unroll
                for (int reg = 0; reg < 4; ++reg)
                    s[reg] = f2bf(O[mt][nt][reg] * rs[mt][reg]);
                Obf[p][mt][nt] = s;
            }
        CFENCE();
    }

    // ---- gather attn outputs into shared Ao[64][264], then O-proj ----
    __syncthreads();
    short* Ao = lds;
#pragma unroll
    for (int p = 0; p < 2; ++p) {
        int h = wid * 2 + p;
#pragma unroll
        for (int mt = 0; mt < 4; ++mt)
#pragma unroll
            for (int nt = 0; nt < 2; ++nt)
#pragma unroll
                for (int reg = 0; reg < 4; ++reg)
                    Ao[(mt * 16 + quad * 4 + reg) * 264 + h * 32 + nt * 16 + l15] =
                        Obf[p][mt][nt][reg];
    }
    __syncthreads();

    int pix[4];
#pragma unroll
    for (int mt = 0; mt < 4; ++mt) pix[mt] = row2pix(win * 64 + mt * 16 + l15);

    floatx4 acc2[4][4];   // [nt][mt]
#pragma unroll
    for (int nt = 0; nt < 4; ++nt)
#pragma unroll
        for (int mt = 0; mt < 4; ++mt) acc2[nt][mt] = (floatx4){0.f, 0.f, 0.f, 0.f};
#pragma unroll
    for (int kt = 0; kt < 8; ++kt) {
        shortx8 bw[4], af2[4];
#pragma unroll
        for (int nt = 0; nt < 4; ++nt)
            bw[nt] = *(const shortx8*)(wof + (size_t)((wid * 4 + nt) * 8 + kt) * 512 + lane * 8);
#pragma unroll
        for (int mt = 0; mt < 4; ++mt)
            af2[mt] = *(const shortx8*)&Ao[(mt * 16 + l15) * 264 + kt * 32 + quad * 8];
#pragma unroll
        for (int nt = 0; nt < 4; ++nt)
#pragma unroll
            for (int mt = 0; mt < 4; ++mt)
                acc2[nt][mt] = __builtin_amdgcn_mfma_f32_16x16x32_bf16(bw[nt], af2[mt], acc2[nt][mt], 0, 0, 0);
    }
#pragma unroll
    for (int nt = 0; nt < 4; ++nt) {
        int nb = wid * 64 + nt * 16 + quad * 4;
        float bs[4];
#pragma unroll
        for (int reg = 0; reg < 4; ++reg) bs[reg] = bo[nb + reg];
#pragma unroll
        for (int mt = 0; mt < 4; ++mt) {
            floatx4 o;
            o[0] = acc2[nt][mt][0] + bs[0];
            o[1] = acc2[nt][mt][1] + bs[1];
            o[2] = acc2[nt][mt][2] + bs[2];
            o[3] = acc2[nt][mt][3] + bs[3];
            __builtin_nontemporal_store(o, (floatx4*)(out + (size_t)pix[mt] * 256 + nb));
        }
    }
}

// ---------------- launch ----------------
extern "C" void kernel_launch(void* const* d_in, const int* in_sizes, int n_in,
                              void* d_out, int out_size, void* d_ws, size_t ws_size,
                              hipStream_t stream) {
    const float* x  = (const float*)d_in[0];
    const float* Wq = (const float*)d_in[1];
    const float* bq = (const float*)d_in[2];
    const float* Wk = (const float*)d_in[3];
    const float* bk = (const float*)d_in[4];
    const float* Wv = (const float*)d_in[5];
    const float* bv = (const float*)d_in[6];
    const float* Wo = (const float*)d_in[7];
    const float* bo = (const float*)d_in[8];
    const float* ls = (const float*)d_in[9];
    const float* w1 = (const float*)d_in[10];
    const float* b1 = (const float*)d_in[11];
    const float* w2 = (const float*)d_in[12];

    char* ws = (char*)d_ws;
    short* wqkv_f = (short*)(ws + 0);           //   393,216 B
    short* wo_f   = (short*)(ws + 393216);      //   131,072 B
    float* bias_t = (float*)(ws + 524288);      //   131,072 B
    float* scale  = (float*)(ws + 655360);      //        32 B
    float* b225g  = (float*)(ws + 786432);      //     7,200 B
    short* xbf    = (short*)(ws + 1048576);     //  33,554,432 B
    float* out    = (float*)d_out;

    hipLaunchKernelGGL(wtrans, dim3(128), dim3(256), 0, stream, Wq, Wk, Wv, Wo, wqkv_f, wo_f);
    hipLaunchKernelGGL(bias_mlp, dim3(225), dim3(256), 0, stream, ls, w1, b1, w2, b225g, scale);
    hipLaunchKernelGGL(bias_expand, dim3(128), dim3(256), 0, stream, b225g, bias_t);
    hipLaunchKernelGGL(xtrans, dim3(1024), dim3(256), 0, stream, x, xbf);
    hipLaunchKernelGGL(swin_fused, dim3(1024), dim3(256), 0, stream,
                       xbf, wqkv_f, wo_f, bq, bk, bv, bo, bias_t, scale, out);
}

// Round 7
// 290.161 us; speedup vs baseline: 1.1774x; 1.1774x over previous
//
#include <hip/hip_runtime.h>
#include <hip/hip_bf16.h>

typedef float floatx4 __attribute__((ext_vector_type(4)));
typedef short shortx8 __attribute__((ext_vector_type(8)));
typedef short shortx4 __attribute__((ext_vector_type(4)));

#define CFENCE() asm volatile("" ::: "memory")

__device__ __forceinline__ float bf2f(short s) {
    union { unsigned u; float f; } cv;
    cv.u = ((unsigned)(unsigned short)s) << 16;
    return cv.f;
}
__device__ __forceinline__ short f2bf(float f) {
    union { float f; unsigned u; } cv; cv.f = f;
    unsigned r = (cv.u + 0x7fffu + ((cv.u >> 16) & 1u)) >> 16;
    return (short)r;
}

// ---------------- K0a: weights -> bf16 fragment-major layout ----------------
__global__ __launch_bounds__(256) void wtrans(const float* __restrict__ Wq,
                                              const float* __restrict__ Wk,
                                              const float* __restrict__ Wv,
                                              const float* __restrict__ Wo,
                                              short* __restrict__ wqkv_f,
                                              short* __restrict__ wo_f) {
    int gtid = blockIdx.x * 256 + threadIdx.x;
    int f = gtid >> 6, lane = gtid & 63;
    int quad = lane >> 4, l15 = lane & 15;
    if (f < 384) {
        int n16 = f >> 3, kt = f & 7;
        int n = n16 * 16 + l15, z = n >> 8, ncol = n & 255;
        const float* src = (z == 0) ? Wq : (z == 1) ? Wk : Wv;
        shortx8 s;
#pragma unroll
        for (int j = 0; j < 8; ++j)
            s[j] = f2bf(src[(size_t)(kt * 32 + quad * 8 + j) * 256 + ncol]);
        *(shortx8*)(wqkv_f + (size_t)f * 512 + lane * 8) = s;
    } else {
        int f2 = f - 384;
        int n16 = f2 >> 3, kt = f2 & 7;
        int n = n16 * 16 + l15;
        shortx8 s;
#pragma unroll
        for (int j = 0; j < 8; ++j)
            s[j] = f2bf(Wo[(size_t)(kt * 32 + quad * 8 + j) * 256 + n]);
        *(shortx8*)(wo_f + (size_t)f2 * 512 + lane * 8) = s;
    }
}

// ---------------- K0b: CPB MLP ----------------
__device__ __forceinline__ float sgnlog(float x) {
    return copysignf(__log2f(fabsf(x) + 1.f) / 3.f, x);
}
__global__ __launch_bounds__(256) void bias_mlp(const float* __restrict__ ls,
                                                const float* __restrict__ w1,
                                                const float* __restrict__ b1,
                                                const float* __restrict__ w2,
                                                float* __restrict__ b225g,
                                                float* __restrict__ scaleOut) {
    int e = blockIdx.x;
    int tid = threadIdx.x, lane = tid & 63, wid = tid >> 6;
    if (e == 0 && tid < 8) scaleOut[tid] = expf(fminf(ls[tid], 4.6051701859880914f));
    int dh = e / 15 - 7, dw = e % 15 - 7;
    float t0 = sgnlog(8.f * (float)dh / 7.f);
    float t1 = sgnlog(8.f * (float)dw / 7.f);
    float acc[8];
#pragma unroll
    for (int j = 0; j < 8; ++j) acc[j] = 0.f;
#pragma unroll
    for (int s = 0; s < 2; ++s) {
        int hsm = tid + s * 256;
        float hid = fmaxf(0.f, t0 * w1[hsm] + t1 * w1[512 + hsm] + b1[hsm]);
#pragma unroll
        for (int j = 0; j < 8; ++j) acc[j] += hid * w2[hsm * 8 + j];
    }
#pragma unroll
    for (int off = 1; off < 64; off <<= 1)
#pragma unroll
        for (int j = 0; j < 8; ++j) acc[j] += __shfl_xor(acc[j], off, 64);
    __shared__ float red[4][8];
    if (lane == 0)
#pragma unroll
        for (int j = 0; j < 8; ++j) red[wid][j] = acc[j];
    __syncthreads();
    if (tid < 8)
        b225g[e * 8 + tid] = red[0][tid] + red[1][tid] + red[2][tid] + red[3][tid];
}

// ---------------- K0c: expand to per-head 64x64 bias, TRANSPOSED [h][j][i] ----------------
__global__ __launch_bounds__(256) void bias_expand(const float* __restrict__ b225g,
                                                   float* __restrict__ bias_t) {
    int f = blockIdx.x * 256 + threadIdx.x;
    int h = f >> 12, ij = f & 4095, i = ij >> 6, j = ij & 63;
    int dh = (i >> 3) - (j >> 3), dw = (i & 7) - (j & 7);
    int e = (dh + 7) * 15 + (dw + 7);
    float v = b225g[e * 8 + h];
    bias_t[(h << 12) + j * 64 + i] = 16.f / (1.f + expf(-v));
}

// token row -> pixel (roll by +4 both ways, same map fwd/bwd)
__device__ __forceinline__ int row2pix(int row) {
    int w = row >> 6, t = row & 63;
    int b = w >> 6, wi = (w >> 3) & 7, wj = w & 7;
    int hh = (wi * 8 + (t >> 3) + 4) & 63;
    int ww = (wj * 8 + (t & 7) + 4) & 63;
    return (b * 64 + hh) * 64 + ww;
}

__device__ __forceinline__ int regid(int t, int wi, int wj) {
    int a = (wi < 7) ? 0 : (((t >> 3) < 4) ? 1 : 2);
    int b = (wj < 7) ? 0 : (((t & 7) < 4) ? 1 : 2);
    return a * 3 + b;
}

// ---------------- K0d: x -> bf16 token-fragment layout ----------------
__global__ __launch_bounds__(256) void xtrans(const float* __restrict__ x,
                                              short* __restrict__ xbf) {
    int win = blockIdx.x;
    int tid = threadIdx.x;
    int r = tid >> 2, q = tid & 3;
    const float* src = x + (size_t)row2pix(win * 64 + r) * 256 + q * 64;
    size_t fb = (size_t)(win * 4 + (r >> 4)) * 8;
    int l15r = r & 15;
#pragma unroll
    for (int kt2 = 0; kt2 < 2; ++kt2) {
        int kt = q * 2 + kt2;
        short* dst = xbf + (fb + kt) * 512 + l15r * 8;
#pragma unroll
        for (int quad = 0; quad < 4; ++quad) {
            float4 u0 = *(const float4*)(src + kt2 * 32 + quad * 8);
            float4 u1 = *(const float4*)(src + kt2 * 32 + quad * 8 + 4);
            shortx8 t;
            t[0] = f2bf(u0.x); t[1] = f2bf(u0.y); t[2] = f2bf(u0.z); t[3] = f2bf(u0.w);
            t[4] = f2bf(u1.x); t[5] = f2bf(u1.y); t[6] = f2bf(u1.z); t[7] = f2bf(u1.w);
            *(shortx8*)(dst + quad * 128) = t;
        }
    }
}

// ---------------- Fused: QKV + attention + O-proj, one block per window ----------------
// Round-3 schedule with: strides 40->34 (qn/kn) and 72->68 (vt/P) [conflict fix, verified
// r6: 1.7M->524K], per-wave 6528 shorts -> 52224 B block LDS -> 3 blocks/CU [verified r6:
// 26.7% occ]. Plain (cached) loads/stores — nontemporal was a measured 2x regression (r6).
__global__ __launch_bounds__(256, 3) void swin_fused(const short* __restrict__ xbf,
                                                     const short* __restrict__ wf,
                                                     const short* __restrict__ wof,
                                                     const float* __restrict__ bq,
                                                     const float* __restrict__ bk_,
                                                     const float* __restrict__ bv,
                                                     const float* __restrict__ bo,
                                                     const float* __restrict__ bias_t,
                                                     const float* __restrict__ scale,
                                                     float* __restrict__ out) {
    __shared__ __align__(16) short lds[26112];   // 52224 B
    int tid = threadIdx.x, lane = tid & 63, wid = tid >> 6;
    int quad = lane >> 4, l15 = lane & 15;
    int win = blockIdx.x;
    int wi = (win >> 3) & 7, wj = win & 7;
    bool need_mask = (wi == 7) || (wj == 7);

    short* qn = &lds[wid * 6528];   // [64][34]  (2176)
    short* kn = qn + 2176;          // [64][34]  (2176)
    short* vt = qn + 4352;          // [32][68]  (2176)
    short* P  = qn;                 // [64][68]  (4352) aliases qn+kn after frags read

    const short* xfb = xbf + (size_t)(win * 4) * 8 * 512 + lane * 8;

    shortx4 Obf[2][4][2];                // per-pass attn output, bf16-packed

#pragma unroll
    for (int p = 0; p < 2; ++p) {
        int h = wid * 2 + p;
        // ---- QKV GEMM (C^T): 24 MFMA per kt ----
        floatx4 aq[2][4], ak[2][4], av[2][4];
#pragma unroll
        for (int i = 0; i < 2; ++i)
#pragma unroll
            for (int mt = 0; mt < 4; ++mt) {
                aq[i][mt] = (floatx4){0.f, 0.f, 0.f, 0.f};
                ak[i][mt] = (floatx4){0.f, 0.f, 0.f, 0.f};
                av[i][mt] = (floatx4){0.f, 0.f, 0.f, 0.f};
            }
#pragma unroll
        for (int kt = 0; kt < 8; ++kt) {
            shortx8 af[4];
#pragma unroll
            for (int mt = 0; mt < 4; ++mt)
                af[mt] = *(const shortx8*)(xfb + (size_t)(mt * 8 + kt) * 512);
            shortx8 wqf[2], wkf[2], wvf[2];
#pragma unroll
            for (int i = 0; i < 2; ++i) {
                int n16 = 2 * h + i;
                wqf[i] = *(const shortx8*)(wf + (size_t)((n16)*8 + kt) * 512 + lane * 8);
                wkf[i] = *(const shortx8*)(wf + (size_t)((16 + n16) * 8 + kt) * 512 + lane * 8);
                wvf[i] = *(const shortx8*)(wf + (size_t)((32 + n16) * 8 + kt) * 512 + lane * 8);
            }
#pragma unroll
            for (int i = 0; i < 2; ++i)
#pragma unroll
                for (int mt = 0; mt < 4; ++mt) {
                    aq[i][mt] = __builtin_amdgcn_mfma_f32_16x16x32_bf16(wqf[i], af[mt], aq[i][mt], 0, 0, 0);
                    ak[i][mt] = __builtin_amdgcn_mfma_f32_16x16x32_bf16(wkf[i], af[mt], ak[i][mt], 0, 0, 0);
                    av[i][mt] = __builtin_amdgcn_mfma_f32_16x16x32_bf16(wvf[i], af[mt], av[i][mt], 0, 0, 0);
                }
        }
        // ---- bias + cosine norms (token = col; sum over quads via shfl) ----
        float sc = scale[h];
        float qs[4], ks[4];
#pragma unroll
        for (int mt = 0; mt < 4; ++mt) { qs[mt] = 0.f; ks[mt] = 0.f; }
#pragma unroll
        for (int i = 0; i < 2; ++i) {
            float bqv[4], bkv[4], bvv[4];
#pragma unroll
            for (int r = 0; r < 4; ++r) {
                int d = i * 16 + quad * 4 + r;
                bqv[r] = bq[h * 32 + d];
                bkv[r] = bk_[h * 32 + d];
                bvv[r] = bv[h * 32 + d];
            }
#pragma unroll
            for (int mt = 0; mt < 4; ++mt)
#pragma unroll
                for (int r = 0; r < 4; ++r) {
                    float qv = aq[i][mt][r] + bqv[r]; aq[i][mt][r] = qv; qs[mt] += qv * qv;
                    float kv = ak[i][mt][r] + bkv[r]; ak[i][mt][r] = kv; ks[mt] += kv * kv;
                    av[i][mt][r] += bvv[r];
                }
        }
#pragma unroll
        for (int mt = 0; mt < 4; ++mt) {
            qs[mt] += __shfl_xor(qs[mt], 16, 64); qs[mt] += __shfl_xor(qs[mt], 32, 64);
            ks[mt] += __shfl_xor(ks[mt], 16, 64); ks[mt] += __shfl_xor(ks[mt], 32, 64);
        }
        CFENCE();
        // ---- write normalized q,k and transposed v into LDS ----
#pragma unroll
        for (int mt = 0; mt < 4; ++mt) {
            float qr = sc / fmaxf(sqrtf(qs[mt]), 1e-12f);
            float kr = 1.f / fmaxf(sqrtf(ks[mt]), 1e-12f);
            int tok = mt * 16 + l15;
#pragma unroll
            for (int i = 0; i < 2; ++i) {
                shortx4 oq, ok;
#pragma unroll
                for (int r = 0; r < 4; ++r) {
                    oq[r] = f2bf(aq[i][mt][r] * qr);
                    ok[r] = f2bf(ak[i][mt][r] * kr);
                }
                *(shortx4*)&qn[tok * 34 + i * 16 + quad * 4] = oq;
                *(shortx4*)&kn[tok * 34 + i * 16 + quad * 4] = ok;
#pragma unroll
                for (int r = 0; r < 4; ++r)
                    vt[(i * 16 + quad * 4 + r) * 68 + tok] = f2bf(av[i][mt][r]);
            }
        }
        CFENCE();
        // ---- QK^T ----
        shortx8 aqf[4], bkf[4];
#pragma unroll
        for (int mt = 0; mt < 4; ++mt)
            aqf[mt] = *(const shortx8*)&qn[(mt * 16 + l15) * 34 + quad * 8];
#pragma unroll
        for (int nt = 0; nt < 4; ++nt)
            bkf[nt] = *(const shortx8*)&kn[(nt * 16 + l15) * 34 + quad * 8];
        floatx4 S[4][4];
#pragma unroll
        for (int mt = 0; mt < 4; ++mt)
#pragma unroll
            for (int nt = 0; nt < 4; ++nt) {
                floatx4 z = {0.f, 0.f, 0.f, 0.f};
                S[mt][nt] = __builtin_amdgcn_mfma_f32_16x16x32_bf16(aqf[mt], bkf[nt], z, 0, 0, 0);
            }
        // ---- softmax (bias via transposed float4 loads) ----
        const float* bh = bias_t + (h << 12);
        float bound = sc + 16.5f;
        int jid[4];
        if (need_mask) {
#pragma unroll
            for (int nt = 0; nt < 4; ++nt) jid[nt] = regid(nt * 16 + l15, wi, wj);
        }
        float rs[4][4];
#pragma unroll
        for (int mt = 0; mt < 4; ++mt) {
            float4 b4[4];
#pragma unroll
            for (int nt = 0; nt < 4; ++nt)
                b4[nt] = *(const float4*)&bh[(nt * 16 + l15) * 64 + mt * 16 + quad * 4];
#pragma unroll
            for (int reg = 0; reg < 4; ++reg) {
                int i = mt * 16 + quad * 4 + reg;
                int iid = need_mask ? regid(i, wi, wj) : 0;
                float rowsum = 0.f;
#pragma unroll
                for (int nt = 0; nt < 4; ++nt) {
                    float bb = (reg == 0) ? b4[nt].x : (reg == 1) ? b4[nt].y
                             : (reg == 2) ? b4[nt].z : b4[nt].w;
                    float v = S[mt][nt][reg] + bb;
                    if (need_mask && iid != jid[nt]) v -= 100.f;
                    float pe = __expf(v - bound);
                    S[mt][nt][reg] = pe;
                    rowsum += pe;
                }
                rowsum += __shfl_xor(rowsum, 1, 64);
                rowsum += __shfl_xor(rowsum, 2, 64);
                rowsum += __shfl_xor(rowsum, 4, 64);
                rowsum += __shfl_xor(rowsum, 8, 64);
                rs[mt][reg] = 1.f / rowsum;
            }
        }
        CFENCE();
        // ---- P into LDS (aliases qn+kn; frags already consumed) ----
#pragma unroll
        for (int mt = 0; mt < 4; ++mt)
#pragma unroll
            for (int nt = 0; nt < 4; ++nt)
#pragma unroll
                for (int reg = 0; reg < 4; ++reg)
                    P[(mt * 16 + quad * 4 + reg) * 68 + nt * 16 + l15] = f2bf(S[mt][nt][reg]);
        CFENCE();
        // ---- PV ----
        floatx4 O[4][2];
#pragma unroll
        for (int mt = 0; mt < 4; ++mt)
#pragma unroll
            for (int nt = 0; nt < 2; ++nt) O[mt][nt] = (floatx4){0.f, 0.f, 0.f, 0.f};
#pragma unroll
        for (int ks2 = 0; ks2 < 2; ++ks2) {
            shortx8 pa[4], vb[2];
#pragma unroll
            for (int mt = 0; mt < 4; ++mt)
                pa[mt] = *(const shortx8*)&P[(mt * 16 + l15) * 68 + ks2 * 32 + quad * 8];
#pragma unroll
            for (int nt = 0; nt < 2; ++nt)
                vb[nt] = *(const shortx8*)&vt[(nt * 16 + l15) * 68 + ks2 * 32 + quad * 8];
#pragma unroll
            for (int mt = 0; mt < 4; ++mt)
#pragma unroll
                for (int nt = 0; nt < 2; ++nt)
                    O[mt][nt] = __builtin_amdgcn_mfma_f32_16x16x32_bf16(pa[mt], vb[nt], O[mt][nt], 0, 0, 0);
        }
        // ---- scale + pack to bf16 immediately ----
#pragma unroll
        for (int mt = 0; mt < 4; ++mt)
#pragma unroll
            for (int nt = 0; nt < 2; ++nt) {
                shortx4 s;
#pragma unroll
                for (int reg = 0; reg < 4; ++reg)
                    s[reg] = f2bf(O[mt][nt][reg] * rs[mt][reg]);
                Obf[p][mt][nt] = s;
            }
        CFENCE();
    }

    // ---- gather attn outputs into shared Ao[64][264], then O-proj ----
    __syncthreads();
    short* Ao = lds;
#pragma unroll
    for (int p = 0; p < 2; ++p) {
        int h = wid * 2 + p;
#pragma unroll
        for (int mt = 0; mt < 4; ++mt)
#pragma unroll
            for (int nt = 0; nt < 2; ++nt)
#pragma unroll
                for (int reg = 0; reg < 4; ++reg)
                    Ao[(mt * 16 + quad * 4 + reg) * 264 + h * 32 + nt * 16 + l15] =
                        Obf[p][mt][nt][reg];
    }
    __syncthreads();

    int pix[4];
#pragma unroll
    for (int mt = 0; mt < 4; ++mt) pix[mt] = row2pix(win * 64 + mt * 16 + l15);

    floatx4 acc2[4][4];   // [nt][mt]
#pragma unroll
    for (int nt = 0; nt < 4; ++nt)
#pragma unroll
        for (int mt = 0; mt < 4; ++mt) acc2[nt][mt] = (floatx4){0.f, 0.f, 0.f, 0.f};
#pragma unroll
    for (int kt = 0; kt < 8; ++kt) {
        shortx8 bw[4], af2[4];
#pragma unroll
        for (int nt = 0; nt < 4; ++nt)
            bw[nt] = *(const shortx8*)(wof + (size_t)((wid * 4 + nt) * 8 + kt) * 512 + lane * 8);
#pragma unroll
        for (int mt = 0; mt < 4; ++mt)
            af2[mt] = *(const shortx8*)&Ao[(mt * 16 + l15) * 264 + kt * 32 + quad * 8];
#pragma unroll
        for (int nt = 0; nt < 4; ++nt)
#pragma unroll
            for (int mt = 0; mt < 4; ++mt)
                acc2[nt][mt] = __builtin_amdgcn_mfma_f32_16x16x32_bf16(bw[nt], af2[mt], acc2[nt][mt], 0, 0, 0);
    }
#pragma unroll
    for (int nt = 0; nt < 4; ++nt) {
        int nb = wid * 64 + nt * 16 + quad * 4;
        float bs[4];
#pragma unroll
        for (int reg = 0; reg < 4; ++reg) bs[reg] = bo[nb + reg];
#pragma unroll
        for (int mt = 0; mt < 4; ++mt) {
            float4 o;
            o.x = acc2[nt][mt][0] + bs[0];
            o.y = acc2[nt][mt][1] + bs[1];
            o.z = acc2[nt][mt][2] + bs[2];
            o.w = acc2[nt][mt][3] + bs[3];
            *(float4*)(out + (size_t)pix[mt] * 256 + nb) = o;
        }
    }
}

// ---------------- launch ----------------
extern "C" void kernel_launch(void* const* d_in, const int* in_sizes, int n_in,
                              void* d_out, int out_size, void* d_ws, size_t ws_size,
                              hipStream_t stream) {
    const float* x  = (const float*)d_in[0];
    const float* Wq = (const float*)d_in[1];
    const float* bq = (const float*)d_in[2];
    const float* Wk = (const float*)d_in[3];
    const float* bk = (const float*)d_in[4];
    const float* Wv = (const float*)d_in[5];
    const float* bv = (const float*)d_in[6];
    const float* Wo = (const float*)d_in[7];
    const float* bo = (const float*)d_in[8];
    const float* ls = (const float*)d_in[9];
    const float* w1 = (const float*)d_in[10];
    const float* b1 = (const float*)d_in[11];
    const float* w2 = (const float*)d_in[12];

    char* ws = (char*)d_ws;
    short* wqkv_f = (short*)(ws + 0);           //   393,216 B
    short* wo_f   = (short*)(ws + 393216);      //   131,072 B
    float* bias_t = (float*)(ws + 524288);      //   131,072 B
    float* scale  = (float*)(ws + 655360);      //        32 B
    float* b225g  = (float*)(ws + 786432);      //     7,200 B
    short* xbf    = (short*)(ws + 1048576);     //  33,554,432 B
    float* out    = (float*)d_out;

    hipLaunchKernelGGL(wtrans, dim3(128), dim3(256), 0, stream, Wq, Wk, Wv, Wo, wqkv_f, wo_f);
    hipLaunchKernelGGL(bias_mlp, dim3(225), dim3(256), 0, stream, ls, w1, b1, w2, b225g, scale);
    hipLaunchKernelGGL(bias_expand, dim3(128), dim3(256), 0, stream, b225g, bias_t);
    hipLaunchKernelGGL(xtrans, dim3(1024), dim3(256), 0, stream, x, xbf);
    hipLaunchKernelGGL(swin_fused, dim3(1024), dim3(256), 0, stream,
                       xbf, wqkv_f, wo_f, bq, bk, bv, bo, bias_t, scale, out);
}

// Round 8
// 240.958 us; speedup vs baseline: 1.4179x; 1.2042x over previous
//
#include <hip/hip_runtime.h>
#include <hip/hip_bf16.h>

typedef float floatx4 __attribute__((ext_vector_type(4)));
typedef short shortx8 __attribute__((ext_vector_type(8)));
typedef short shortx4 __attribute__((ext_vector_type(4)));

#define CFENCE() asm volatile("" ::: "memory")

__device__ __forceinline__ float bf2f(short s) {
    union { unsigned u; float f; } cv;
    cv.u = ((unsigned)(unsigned short)s) << 16;
    return cv.f;
}
__device__ __forceinline__ short f2bf(float f) {
    union { float f; unsigned u; } cv; cv.f = f;
    unsigned r = (cv.u + 0x7fffu + ((cv.u >> 16) & 1u)) >> 16;
    return (short)r;
}

// ---------------- K0a: weights -> bf16 fragment-major layout ----------------
__global__ __launch_bounds__(256) void wtrans(const float* __restrict__ Wq,
                                              const float* __restrict__ Wk,
                                              const float* __restrict__ Wv,
                                              const float* __restrict__ Wo,
                                              short* __restrict__ wqkv_f,
                                              short* __restrict__ wo_f) {
    int gtid = blockIdx.x * 256 + threadIdx.x;
    int f = gtid >> 6, lane = gtid & 63;
    int quad = lane >> 4, l15 = lane & 15;
    if (f < 384) {
        int n16 = f >> 3, kt = f & 7;
        int n = n16 * 16 + l15, z = n >> 8, ncol = n & 255;
        const float* src = (z == 0) ? Wq : (z == 1) ? Wk : Wv;
        shortx8 s;
#pragma unroll
        for (int j = 0; j < 8; ++j)
            s[j] = f2bf(src[(size_t)(kt * 32 + quad * 8 + j) * 256 + ncol]);
        *(shortx8*)(wqkv_f + (size_t)f * 512 + lane * 8) = s;
    } else {
        int f2 = f - 384;
        int n16 = f2 >> 3, kt = f2 & 7;
        int n = n16 * 16 + l15;
        shortx8 s;
#pragma unroll
        for (int j = 0; j < 8; ++j)
            s[j] = f2bf(Wo[(size_t)(kt * 32 + quad * 8 + j) * 256 + n]);
        *(shortx8*)(wo_f + (size_t)f2 * 512 + lane * 8) = s;
    }
}

// ---------------- K0b: CPB MLP ----------------
__device__ __forceinline__ float sgnlog(float x) {
    return copysignf(__log2f(fabsf(x) + 1.f) / 3.f, x);
}
__global__ __launch_bounds__(256) void bias_mlp(const float* __restrict__ ls,
                                                const float* __restrict__ w1,
                                                const float* __restrict__ b1,
                                                const float* __restrict__ w2,
                                                float* __restrict__ b225g,
                                                float* __restrict__ scaleOut) {
    int e = blockIdx.x;
    int tid = threadIdx.x, lane = tid & 63, wid = tid >> 6;
    if (e == 0 && tid < 8) scaleOut[tid] = expf(fminf(ls[tid], 4.6051701859880914f));
    int dh = e / 15 - 7, dw = e % 15 - 7;
    float t0 = sgnlog(8.f * (float)dh / 7.f);
    float t1 = sgnlog(8.f * (float)dw / 7.f);
    float acc[8];
#pragma unroll
    for (int j = 0; j < 8; ++j) acc[j] = 0.f;
#pragma unroll
    for (int s = 0; s < 2; ++s) {
        int hsm = tid + s * 256;
        float hid = fmaxf(0.f, t0 * w1[hsm] + t1 * w1[512 + hsm] + b1[hsm]);
#pragma unroll
        for (int j = 0; j < 8; ++j) acc[j] += hid * w2[hsm * 8 + j];
    }
#pragma unroll
    for (int off = 1; off < 64; off <<= 1)
#pragma unroll
        for (int j = 0; j < 8; ++j) acc[j] += __shfl_xor(acc[j], off, 64);
    __shared__ float red[4][8];
    if (lane == 0)
#pragma unroll
        for (int j = 0; j < 8; ++j) red[wid][j] = acc[j];
    __syncthreads();
    if (tid < 8)
        b225g[e * 8 + tid] = red[0][tid] + red[1][tid] + red[2][tid] + red[3][tid];
}

// ---------------- K0c: expand to per-head 64x64 bias, TRANSPOSED [h][j][i] ----------------
__global__ __launch_bounds__(256) void bias_expand(const float* __restrict__ b225g,
                                                   float* __restrict__ bias_t) {
    int f = blockIdx.x * 256 + threadIdx.x;
    int h = f >> 12, ij = f & 4095, i = ij >> 6, j = ij & 63;
    int dh = (i >> 3) - (j >> 3), dw = (i & 7) - (j & 7);
    int e = (dh + 7) * 15 + (dw + 7);
    float v = b225g[e * 8 + h];
    bias_t[(h << 12) + j * 64 + i] = 16.f / (1.f + expf(-v));
}

// token row -> pixel (roll by +4 both ways, same map fwd/bwd)
__device__ __forceinline__ int row2pix(int row) {
    int w = row >> 6, t = row & 63;
    int b = w >> 6, wi = (w >> 3) & 7, wj = w & 7;
    int hh = (wi * 8 + (t >> 3) + 4) & 63;
    int ww = (wj * 8 + (t & 7) + 4) & 63;
    return (b * 64 + hh) * 64 + ww;
}

__device__ __forceinline__ int regid(int t, int wi, int wj) {
    int a = (wi < 7) ? 0 : (((t >> 3) < 4) ? 1 : 2);
    int b = (wj < 7) ? 0 : (((t & 7) < 4) ? 1 : 2);
    return a * 3 + b;
}

// ---------------- K0d: x -> bf16 token-fragment layout ----------------
__global__ __launch_bounds__(256) void xtrans(const float* __restrict__ x,
                                              short* __restrict__ xbf) {
    int win = blockIdx.x;
    int tid = threadIdx.x;
    int r = tid >> 2, q = tid & 3;
    const float* src = x + (size_t)row2pix(win * 64 + r) * 256 + q * 64;
    size_t fb = (size_t)(win * 4 + (r >> 4)) * 8;
    int l15r = r & 15;
#pragma unroll
    for (int kt2 = 0; kt2 < 2; ++kt2) {
        int kt = q * 2 + kt2;
        short* dst = xbf + (fb + kt) * 512 + l15r * 8;
#pragma unroll
        for (int quad = 0; quad < 4; ++quad) {
            float4 u0 = *(const float4*)(src + kt2 * 32 + quad * 8);
            float4 u1 = *(const float4*)(src + kt2 * 32 + quad * 8 + 4);
            shortx8 t;
            t[0] = f2bf(u0.x); t[1] = f2bf(u0.y); t[2] = f2bf(u0.z); t[3] = f2bf(u0.w);
            t[4] = f2bf(u1.x); t[5] = f2bf(u1.y); t[6] = f2bf(u1.z); t[7] = f2bf(u1.w);
            *(shortx8*)(dst + quad * 128) = t;
        }
    }
}

// ---------------- Fused: QKV + attention + O-proj, one block per window ----------------
// VGPR discipline (r7 finding: effective cap = 256/min_waves; (256,3) -> 84 caused the
// spill storm): launch_bounds(256,2) -> cap 128, and QKV split into QK phase (~116 live)
// and V phase (~70 live) so no phase exceeds 128. Strides 34/68 keep LDS conflicts at
// ~0.5M (verified r6/r7). LDS 52224 B; occupancy 2 blocks/CU (VGPR-limited).
__global__ __launch_bounds__(256, 2) void swin_fused(const short* __restrict__ xbf,
                                                     const short* __restrict__ wf,
                                                     const short* __restrict__ wof,
                                                     const float* __restrict__ bq,
                                                     const float* __restrict__ bk_,
                                                     const float* __restrict__ bv,
                                                     const float* __restrict__ bo,
                                                     const float* __restrict__ bias_t,
                                                     const float* __restrict__ scale,
                                                     float* __restrict__ out) {
    __shared__ __align__(16) short lds[26112];   // 52224 B
    int tid = threadIdx.x, lane = tid & 63, wid = tid >> 6;
    int quad = lane >> 4, l15 = lane & 15;
    int win = blockIdx.x;
    int wi = (win >> 3) & 7, wj = win & 7;
    bool need_mask = (wi == 7) || (wj == 7);

    short* qn = &lds[wid * 6528];   // [64][34]  (2176)
    short* kn = qn + 2176;          // [64][34]  (2176)
    short* vt = qn + 4352;          // [32][68]  (2176)
    short* P  = qn;                 // [64][68]  (4352) aliases qn+kn after frags read

    const short* xfb = xbf + (size_t)(win * 4) * 8 * 512 + lane * 8;

    shortx4 Obf[2][4][2];                // per-pass attn output, bf16-packed

#pragma unroll
    for (int p = 0; p < 2; ++p) {
        int h = wid * 2 + p;
        float sc = scale[h];
        // ======== QK GEMM (C^T): 16 MFMA per kt, peak ~116 regs ========
        floatx4 aq[2][4], ak[2][4];
#pragma unroll
        for (int i = 0; i < 2; ++i)
#pragma unroll
            for (int mt = 0; mt < 4; ++mt) {
                aq[i][mt] = (floatx4){0.f, 0.f, 0.f, 0.f};
                ak[i][mt] = (floatx4){0.f, 0.f, 0.f, 0.f};
            }
#pragma unroll
        for (int kt = 0; kt < 8; ++kt) {
            shortx8 af[4];
#pragma unroll
            for (int mt = 0; mt < 4; ++mt)
                af[mt] = *(const shortx8*)(xfb + (size_t)(mt * 8 + kt) * 512);
            shortx8 wqf[2], wkf[2];
#pragma unroll
            for (int i = 0; i < 2; ++i) {
                int n16 = 2 * h + i;
                wqf[i] = *(const shortx8*)(wf + (size_t)((n16)*8 + kt) * 512 + lane * 8);
                wkf[i] = *(const shortx8*)(wf + (size_t)((16 + n16) * 8 + kt) * 512 + lane * 8);
            }
#pragma unroll
            for (int i = 0; i < 2; ++i)
#pragma unroll
                for (int mt = 0; mt < 4; ++mt) {
                    aq[i][mt] = __builtin_amdgcn_mfma_f32_16x16x32_bf16(wqf[i], af[mt], aq[i][mt], 0, 0, 0);
                    ak[i][mt] = __builtin_amdgcn_mfma_f32_16x16x32_bf16(wkf[i], af[mt], ak[i][mt], 0, 0, 0);
                }
        }
        // ---- bias + cosine norms (token = col; sum over quads via shfl) ----
        float qs[4], ks[4];
#pragma unroll
        for (int mt = 0; mt < 4; ++mt) { qs[mt] = 0.f; ks[mt] = 0.f; }
#pragma unroll
        for (int i = 0; i < 2; ++i) {
            float bqv[4], bkv[4];
#pragma unroll
            for (int r = 0; r < 4; ++r) {
                int d = i * 16 + quad * 4 + r;
                bqv[r] = bq[h * 32 + d];
                bkv[r] = bk_[h * 32 + d];
            }
#pragma unroll
            for (int mt = 0; mt < 4; ++mt)
#pragma unroll
                for (int r = 0; r < 4; ++r) {
                    float qv = aq[i][mt][r] + bqv[r]; aq[i][mt][r] = qv; qs[mt] += qv * qv;
                    float kv = ak[i][mt][r] + bkv[r]; ak[i][mt][r] = kv; ks[mt] += kv * kv;
                }
        }
#pragma unroll
        for (int mt = 0; mt < 4; ++mt) {
            qs[mt] += __shfl_xor(qs[mt], 16, 64); qs[mt] += __shfl_xor(qs[mt], 32, 64);
            ks[mt] += __shfl_xor(ks[mt], 16, 64); ks[mt] += __shfl_xor(ks[mt], 32, 64);
        }
        CFENCE();
        // ---- write normalized q,k into LDS (frees aq/ak) ----
#pragma unroll
        for (int mt = 0; mt < 4; ++mt) {
            float qr = sc / fmaxf(sqrtf(qs[mt]), 1e-12f);
            float kr = 1.f / fmaxf(sqrtf(ks[mt]), 1e-12f);
            int tok = mt * 16 + l15;
#pragma unroll
            for (int i = 0; i < 2; ++i) {
                shortx4 oq, ok;
#pragma unroll
                for (int r = 0; r < 4; ++r) {
                    oq[r] = f2bf(aq[i][mt][r] * qr);
                    ok[r] = f2bf(ak[i][mt][r] * kr);
                }
                *(shortx4*)&qn[tok * 34 + i * 16 + quad * 4] = oq;
                *(shortx4*)&kn[tok * 34 + i * 16 + quad * 4] = ok;
            }
        }
        CFENCE();
        // ======== V GEMM (8 MFMA per kt, af reloaded L2-hot, peak ~70 regs) ========
        floatx4 av[2][4];
#pragma unroll
        for (int i = 0; i < 2; ++i)
#pragma unroll
            for (int mt = 0; mt < 4; ++mt) av[i][mt] = (floatx4){0.f, 0.f, 0.f, 0.f};
#pragma unroll
        for (int kt = 0; kt < 8; ++kt) {
            shortx8 af[4];
#pragma unroll
            for (int mt = 0; mt < 4; ++mt)
                af[mt] = *(const shortx8*)(xfb + (size_t)(mt * 8 + kt) * 512);
            shortx8 wvf[2];
#pragma unroll
            for (int i = 0; i < 2; ++i) {
                int n16 = 2 * h + i;
                wvf[i] = *(const shortx8*)(wf + (size_t)((32 + n16) * 8 + kt) * 512 + lane * 8);
            }
#pragma unroll
            for (int i = 0; i < 2; ++i)
#pragma unroll
                for (int mt = 0; mt < 4; ++mt)
                    av[i][mt] = __builtin_amdgcn_mfma_f32_16x16x32_bf16(wvf[i], af[mt], av[i][mt], 0, 0, 0);
        }
        // ---- bias + write transposed v into LDS ----
#pragma unroll
        for (int i = 0; i < 2; ++i) {
            float bvv[4];
#pragma unroll
            for (int r = 0; r < 4; ++r) bvv[r] = bv[h * 32 + i * 16 + quad * 4 + r];
#pragma unroll
            for (int mt = 0; mt < 4; ++mt) {
                int tok = mt * 16 + l15;
#pragma unroll
                for (int r = 0; r < 4; ++r)
                    vt[(i * 16 + quad * 4 + r) * 68 + tok] = f2bf(av[i][mt][r] + bvv[r]);
            }
        }
        CFENCE();
        // ======== QK^T ========
        shortx8 aqf[4], bkf[4];
#pragma unroll
        for (int mt = 0; mt < 4; ++mt)
            aqf[mt] = *(const shortx8*)&qn[(mt * 16 + l15) * 34 + quad * 8];
#pragma unroll
        for (int nt = 0; nt < 4; ++nt)
            bkf[nt] = *(const shortx8*)&kn[(nt * 16 + l15) * 34 + quad * 8];
        floatx4 S[4][4];
#pragma unroll
        for (int mt = 0; mt < 4; ++mt)
#pragma unroll
            for (int nt = 0; nt < 4; ++nt) {
                floatx4 z = {0.f, 0.f, 0.f, 0.f};
                S[mt][nt] = __builtin_amdgcn_mfma_f32_16x16x32_bf16(aqf[mt], bkf[nt], z, 0, 0, 0);
            }
        // ======== softmax (bias via transposed float4 loads) ========
        const float* bh = bias_t + (h << 12);
        float bound = sc + 16.5f;
        int jid[4];
        if (need_mask) {
#pragma unroll
            for (int nt = 0; nt < 4; ++nt) jid[nt] = regid(nt * 16 + l15, wi, wj);
        }
        float rs[4][4];
#pragma unroll
        for (int mt = 0; mt < 4; ++mt) {
            float4 b4[4];
#pragma unroll
            for (int nt = 0; nt < 4; ++nt)
                b4[nt] = *(const float4*)&bh[(nt * 16 + l15) * 64 + mt * 16 + quad * 4];
#pragma unroll
            for (int reg = 0; reg < 4; ++reg) {
                int i = mt * 16 + quad * 4 + reg;
                int iid = need_mask ? regid(i, wi, wj) : 0;
                float rowsum = 0.f;
#pragma unroll
                for (int nt = 0; nt < 4; ++nt) {
                    float bb = (reg == 0) ? b4[nt].x : (reg == 1) ? b4[nt].y
                             : (reg == 2) ? b4[nt].z : b4[nt].w;
                    float v = S[mt][nt][reg] + bb;
                    if (need_mask && iid != jid[nt]) v -= 100.f;
                    float pe = __expf(v - bound);
                    S[mt][nt][reg] = pe;
                    rowsum += pe;
                }
                rowsum += __shfl_xor(rowsum, 1, 64);
                rowsum += __shfl_xor(rowsum, 2, 64);
                rowsum += __shfl_xor(rowsum, 4, 64);
                rowsum += __shfl_xor(rowsum, 8, 64);
                rs[mt][reg] = 1.f / rowsum;
            }
        }
        CFENCE();
        // ---- P into LDS (aliases qn+kn; frags already consumed) ----
#pragma unroll
        for (int mt = 0; mt < 4; ++mt)
#pragma unroll
            for (int nt = 0; nt < 4; ++nt)
#pragma unroll
                for (int reg = 0; reg < 4; ++reg)
                    P[(mt * 16 + quad * 4 + reg) * 68 + nt * 16 + l15] = f2bf(S[mt][nt][reg]);
        CFENCE();
        // ======== PV ========
        floatx4 O[4][2];
#pragma unroll
        for (int mt = 0; mt < 4; ++mt)
#pragma unroll
            for (int nt = 0; nt < 2; ++nt) O[mt][nt] = (floatx4){0.f, 0.f, 0.f, 0.f};
#pragma unroll
        for (int ks2 = 0; ks2 < 2; ++ks2) {
            shortx8 pa[4], vb[2];
#pragma unroll
            for (int mt = 0; mt < 4; ++mt)
                pa[mt] = *(const shortx8*)&P[(mt * 16 + l15) * 68 + ks2 * 32 + quad * 8];
#pragma unroll
            for (int nt = 0; nt < 2; ++nt)
                vb[nt] = *(const shortx8*)&vt[(nt * 16 + l15) * 68 + ks2 * 32 + quad * 8];
#pragma unroll
            for (int mt = 0; mt < 4; ++mt)
#pragma unroll
                for (int nt = 0; nt < 2; ++nt)
                    O[mt][nt] = __builtin_amdgcn_mfma_f32_16x16x32_bf16(pa[mt], vb[nt], O[mt][nt], 0, 0, 0);
        }
        // ---- scale + pack to bf16 immediately ----
#pragma unroll
        for (int mt = 0; mt < 4; ++mt)
#pragma unroll
            for (int nt = 0; nt < 2; ++nt) {
                shortx4 s;
#pragma unroll
                for (int reg = 0; reg < 4; ++reg)
                    s[reg] = f2bf(O[mt][nt][reg] * rs[mt][reg]);
                Obf[p][mt][nt] = s;
            }
        CFENCE();
    }

    // ---- gather attn outputs into shared Ao[64][264], then O-proj ----
    __syncthreads();
    short* Ao = lds;
#pragma unroll
    for (int p = 0; p < 2; ++p) {
        int h = wid * 2 + p;
#pragma unroll
        for (int mt = 0; mt < 4; ++mt)
#pragma unroll
            for (int nt = 0; nt < 2; ++nt)
#pragma unroll
                for (int reg = 0; reg < 4; ++reg)
                    Ao[(mt * 16 + quad * 4 + reg) * 264 + h * 32 + nt * 16 + l15] =
                        Obf[p][mt][nt][reg];
    }
    __syncthreads();

    int pix[4];
#pragma unroll
    for (int mt = 0; mt < 4; ++mt) pix[mt] = row2pix(win * 64 + mt * 16 + l15);

    floatx4 acc2[4][4];   // [nt][mt]
#pragma unroll
    for (int nt = 0; nt < 4; ++nt)
#pragma unroll
        for (int mt = 0; mt < 4; ++mt) acc2[nt][mt] = (floatx4){0.f, 0.f, 0.f, 0.f};
#pragma unroll
    for (int kt = 0; kt < 8; ++kt) {
        shortx8 bw[4], af2[4];
#pragma unroll
        for (int nt = 0; nt < 4; ++nt)
            bw[nt] = *(const shortx8*)(wof + (size_t)((wid * 4 + nt) * 8 + kt) * 512 + lane * 8);
#pragma unroll
        for (int mt = 0; mt < 4; ++mt)
            af2[mt] = *(const shortx8*)&Ao[(mt * 16 + l15) * 264 + kt * 32 + quad * 8];
#pragma unroll
        for (int nt = 0; nt < 4; ++nt)
#pragma unroll
            for (int mt = 0; mt < 4; ++mt)
                acc2[nt][mt] = __builtin_amdgcn_mfma_f32_16x16x32_bf16(bw[nt], af2[mt], acc2[nt][mt], 0, 0, 0);
    }
#pragma unroll
    for (int nt = 0; nt < 4; ++nt) {
        int nb = wid * 64 + nt * 16 + quad * 4;
        float bs[4];
#pragma unroll
        for (int reg = 0; reg < 4; ++reg) bs[reg] = bo[nb + reg];
#pragma unroll
        for (int mt = 0; mt < 4; ++mt) {
            float4 o;
            o.x = acc2[nt][mt][0] + bs[0];
            o.y = acc2[nt][mt][1] + bs[1];
            o.z = acc2[nt][mt][2] + bs[2];
            o.w = acc2[nt][mt][3] + bs[3];
            *(float4*)(out + (size_t)pix[mt] * 256 + nb) = o;
        }
    }
}

// ---------------- launch ----------------
extern "C" void kernel_launch(void* const* d_in, const int* in_sizes, int n_in,
                              void* d_out, int out_size, void* d_ws, size_t ws_size,
                              hipStream_t stream) {
    const float* x  = (const float*)d_in[0];
    const float* Wq = (const float*)d_in[1];
    const float* bq = (const float*)d_in[2];
    const float* Wk = (const float*)d_in[3];
    const float* bk = (const float*)d_in[4];
    const float* Wv = (const float*)d_in[5];
    const float* bv = (const float*)d_in[6];
    const float* Wo = (const float*)d_in[7];
    const float* bo = (const float*)d_in[8];
    const float* ls = (const float*)d_in[9];
    const float* w1 = (const float*)d_in[10];
    const float* b1 = (const float*)d_in[11];
    const float* w2 = (const float*)d_in[12];

    char* ws = (char*)d_ws;
    short* wqkv_f = (short*)(ws + 0);           //   393,216 B
    short* wo_f   = (short*)(ws + 393216);      //   131,072 B
    float* bias_t = (float*)(ws + 524288);      //   131,072 B
    float* scale  = (float*)(ws + 655360);      //        32 B
    float* b225g  = (float*)(ws + 786432);      //     7,200 B
    short* xbf    = (short*)(ws + 1048576);     //  33,554,432 B
    float* out    = (float*)d_out;

    hipLaunchKernelGGL(wtrans, dim3(128), dim3(256), 0, stream, Wq, Wk, Wv, Wo, wqkv_f, wo_f);
    hipLaunchKernelGGL(bias_mlp, dim3(225), dim3(256), 0, stream, ls, w1, b1, w2, b225g, scale);
    hipLaunchKernelGGL(bias_expand, dim3(128), dim3(256), 0, stream, b225g, bias_t);
    hipLaunchKernelGGL(xtrans, dim3(1024), dim3(256), 0, stream, x, xbf);
    hipLaunchKernelGGL(swin_fused, dim3(1024), dim3(256), 0, stream,
                       xbf, wqkv_f, wo_f, bq, bk, bv, bo, bias_t, scale, out);
}

// Round 9
// 225.878 us; speedup vs baseline: 1.5125x; 1.0668x over previous
//
#include <hip/hip_runtime.h>
#include <hip/hip_bf16.h>

typedef float floatx4 __attribute__((ext_vector_type(4)));
typedef short shortx8 __attribute__((ext_vector_type(8)));
typedef short shortx4 __attribute__((ext_vector_type(4)));

#define CFENCE() asm volatile("" ::: "memory")

__device__ __forceinline__ float bf2f(short s) {
    union { unsigned u; float f; } cv;
    cv.u = ((unsigned)(unsigned short)s) << 16;
    return cv.f;
}
__device__ __forceinline__ short f2bf(float f) {
    union { float f; unsigned u; } cv; cv.f = f;
    unsigned r = (cv.u + 0x7fffu + ((cv.u >> 16) & 1u)) >> 16;
    return (short)r;
}

// ---------------- K0a: weights -> bf16 fragment-major layout ----------------
__global__ __launch_bounds__(256) void wtrans(const float* __restrict__ Wq,
                                              const float* __restrict__ Wk,
                                              const float* __restrict__ Wv,
                                              const float* __restrict__ Wo,
                                              short* __restrict__ wqkv_f,
                                              short* __restrict__ wo_f) {
    int gtid = blockIdx.x * 256 + threadIdx.x;
    int f = gtid >> 6, lane = gtid & 63;
    int quad = lane >> 4, l15 = lane & 15;
    if (f < 384) {
        int n16 = f >> 3, kt = f & 7;
        int n = n16 * 16 + l15, z = n >> 8, ncol = n & 255;
        const float* src = (z == 0) ? Wq : (z == 1) ? Wk : Wv;
        shortx8 s;
#pragma unroll
        for (int j = 0; j < 8; ++j)
            s[j] = f2bf(src[(size_t)(kt * 32 + quad * 8 + j) * 256 + ncol]);
        *(shortx8*)(wqkv_f + (size_t)f * 512 + lane * 8) = s;
    } else {
        int f2 = f - 384;
        int n16 = f2 >> 3, kt = f2 & 7;
        int n = n16 * 16 + l15;
        shortx8 s;
#pragma unroll
        for (int j = 0; j < 8; ++j)
            s[j] = f2bf(Wo[(size_t)(kt * 32 + quad * 8 + j) * 256 + n]);
        *(shortx8*)(wo_f + (size_t)f2 * 512 + lane * 8) = s;
    }
}

// ---------------- K0b: CPB MLP ----------------
__device__ __forceinline__ float sgnlog(float x) {
    return copysignf(__log2f(fabsf(x) + 1.f) / 3.f, x);
}
__global__ __launch_bounds__(256) void bias_mlp(const float* __restrict__ ls,
                                                const float* __restrict__ w1,
                                                const float* __restrict__ b1,
                                                const float* __restrict__ w2,
                                                float* __restrict__ b225g,
                                                float* __restrict__ scaleOut) {
    int e = blockIdx.x;
    int tid = threadIdx.x, lane = tid & 63, wid = tid >> 6;
    if (e == 0 && tid < 8) scaleOut[tid] = expf(fminf(ls[tid], 4.6051701859880914f));
    int dh = e / 15 - 7, dw = e % 15 - 7;
    float t0 = sgnlog(8.f * (float)dh / 7.f);
    float t1 = sgnlog(8.f * (float)dw / 7.f);
    float acc[8];
#pragma unroll
    for (int j = 0; j < 8; ++j) acc[j] = 0.f;
#pragma unroll
    for (int s = 0; s < 2; ++s) {
        int hsm = tid + s * 256;
        float hid = fmaxf(0.f, t0 * w1[hsm] + t1 * w1[512 + hsm] + b1[hsm]);
#pragma unroll
        for (int j = 0; j < 8; ++j) acc[j] += hid * w2[hsm * 8 + j];
    }
#pragma unroll
    for (int off = 1; off < 64; off <<= 1)
#pragma unroll
        for (int j = 0; j < 8; ++j) acc[j] += __shfl_xor(acc[j], off, 64);
    __shared__ float red[4][8];
    if (lane == 0)
#pragma unroll
        for (int j = 0; j < 8; ++j) red[wid][j] = acc[j];
    __syncthreads();
    if (tid < 8)
        b225g[e * 8 + tid] = red[0][tid] + red[1][tid] + red[2][tid] + red[3][tid];
}

// ---------------- K0c: expand to per-head 64x64 bias, TRANSPOSED [h][j][i] ----------------
__global__ __launch_bounds__(256) void bias_expand(const float* __restrict__ b225g,
                                                   float* __restrict__ bias_t) {
    int f = blockIdx.x * 256 + threadIdx.x;
    int h = f >> 12, ij = f & 4095, i = ij >> 6, j = ij & 63;
    int dh = (i >> 3) - (j >> 3), dw = (i & 7) - (j & 7);
    int e = (dh + 7) * 15 + (dw + 7);
    float v = b225g[e * 8 + h];
    bias_t[(h << 12) + j * 64 + i] = 16.f / (1.f + expf(-v));
}

// token row -> pixel (roll by +4 both ways, same map fwd/bwd)
__device__ __forceinline__ int row2pix(int row) {
    int w = row >> 6, t = row & 63;
    int b = w >> 6, wi = (w >> 3) & 7, wj = w & 7;
    int hh = (wi * 8 + (t >> 3) + 4) & 63;
    int ww = (wj * 8 + (t & 7) + 4) & 63;
    return (b * 64 + hh) * 64 + ww;
}

__device__ __forceinline__ int regid(int t, int wi, int wj) {
    int a = (wi < 7) ? 0 : (((t >> 3) < 4) ? 1 : 2);
    int b = (wj < 7) ? 0 : (((t & 7) < 4) ? 1 : 2);
    return a * 3 + b;
}

// ---------------- Fused: QKV + attention + O-proj, one 512-thread block per window ----
// 8 waves, ONE head per wave (h = wid), single pass — halves the per-wave serial chain
// vs r8. x-tile staged ONCE in LDS (fp32->bf16, frag-major) so every af fragment read is
// a conflict-free ds_read_b128 instead of a ~200cy global load (kills r8's 16x VMEM
// redundancy); xtrans kernel + xbf round-trip deleted. VGPR discipline (r7/r8 finding:
// cap = 256/min_waves): launch_bounds(512,2) -> cap 128; QK phase ~112 live, V ~64.
// LDS: xtile 32KB + 8 x 13056B wave scratch = 137216 B (<=160KB/WG on gfx950) -> 1 block
// (8 waves)/CU, same wave count as r8's 2x4. Ao[64][264] aliases xtile after barrier.
__global__ __launch_bounds__(512, 2) void swin_fused(const float* __restrict__ x,
                                                     const short* __restrict__ wf,
                                                     const short* __restrict__ wof,
                                                     const float* __restrict__ bq,
                                                     const float* __restrict__ bk_,
                                                     const float* __restrict__ bv,
                                                     const float* __restrict__ bo,
                                                     const float* __restrict__ bias_t,
                                                     const float* __restrict__ scale,
                                                     float* __restrict__ out) {
    __shared__ __align__(16) short lds[68608];   // 137216 B
    int tid = threadIdx.x, lane = tid & 63, wid = tid >> 6;   // wid 0..7
    int quad = lane >> 4, l15 = lane & 15;
    int win = blockIdx.x;
    int wi = (win >> 3) & 7, wj = win & 7;
    bool need_mask = (wi == 7) || (wj == 7);

    short* xtile = lds;                       // 16384 shorts (32 KB), frag-major
    short* qn = &lds[16384 + wid * 6528];     // [64][34]  (2176)
    short* kn = qn + 2176;                    // [64][34]  (2176)
    short* vt = qn + 4352;                    // [32][68]  (2176)
    short* P  = qn;                           // [64][68]  (4352) aliases qn+kn

    // ---- stage x -> xtile (fp32 gather -> bf16 frag-major), once per block ----
    {
        int r = tid >> 3, seg = tid & 7;      // token r, kt-segment seg
        const float* src = x + (size_t)row2pix(win * 64 + r) * 256 + seg * 32;
        short* dst = &xtile[((r >> 4) * 8 + seg) * 512 + (r & 15) * 8];
#pragma unroll
        for (int c4 = 0; c4 < 4; ++c4) {
            float4 u0 = *(const float4*)(src + c4 * 8);
            float4 u1 = *(const float4*)(src + c4 * 8 + 4);
            shortx8 t;
            t[0] = f2bf(u0.x); t[1] = f2bf(u0.y); t[2] = f2bf(u0.z); t[3] = f2bf(u0.w);
            t[4] = f2bf(u1.x); t[5] = f2bf(u1.y); t[6] = f2bf(u1.z); t[7] = f2bf(u1.w);
            *(shortx8*)(dst + c4 * 128) = t;
        }
    }
    __syncthreads();

    int h = wid;
    float sc = scale[h];

    // ======== QK GEMM (C^T): af from LDS, 16 MFMA per kt, peak ~112 regs ========
    floatx4 aq[2][4], ak[2][4];
#pragma unroll
    for (int i = 0; i < 2; ++i)
#pragma unroll
        for (int mt = 0; mt < 4; ++mt) {
            aq[i][mt] = (floatx4){0.f, 0.f, 0.f, 0.f};
            ak[i][mt] = (floatx4){0.f, 0.f, 0.f, 0.f};
        }
#pragma unroll
    for (int kt = 0; kt < 8; ++kt) {
        shortx8 af[4];
#pragma unroll
        for (int mt = 0; mt < 4; ++mt)
            af[mt] = *(const shortx8*)&xtile[(mt * 8 + kt) * 512 + lane * 8];
        shortx8 wqf[2], wkf[2];
#pragma unroll
        for (int i = 0; i < 2; ++i) {
            int n16 = 2 * h + i;
            wqf[i] = *(const shortx8*)(wf + (size_t)((n16)*8 + kt) * 512 + lane * 8);
            wkf[i] = *(const shortx8*)(wf + (size_t)((16 + n16) * 8 + kt) * 512 + lane * 8);
        }
#pragma unroll
        for (int i = 0; i < 2; ++i)
#pragma unroll
            for (int mt = 0; mt < 4; ++mt) {
                aq[i][mt] = __builtin_amdgcn_mfma_f32_16x16x32_bf16(wqf[i], af[mt], aq[i][mt], 0, 0, 0);
                ak[i][mt] = __builtin_amdgcn_mfma_f32_16x16x32_bf16(wkf[i], af[mt], ak[i][mt], 0, 0, 0);
            }
    }
    // ---- bias + cosine norms (token = col; sum over quads via shfl) ----
    float qs[4], ks[4];
#pragma unroll
    for (int mt = 0; mt < 4; ++mt) { qs[mt] = 0.f; ks[mt] = 0.f; }
#pragma unroll
    for (int i = 0; i < 2; ++i) {
        float bqv[4], bkv[4];
#pragma unroll
        for (int r = 0; r < 4; ++r) {
            int d = i * 16 + quad * 4 + r;
            bqv[r] = bq[h * 32 + d];
            bkv[r] = bk_[h * 32 + d];
        }
#pragma unroll
        for (int mt = 0; mt < 4; ++mt)
#pragma unroll
            for (int r = 0; r < 4; ++r) {
                float qv = aq[i][mt][r] + bqv[r]; aq[i][mt][r] = qv; qs[mt] += qv * qv;
                float kv = ak[i][mt][r] + bkv[r]; ak[i][mt][r] = kv; ks[mt] += kv * kv;
            }
    }
#pragma unroll
    for (int mt = 0; mt < 4; ++mt) {
        qs[mt] += __shfl_xor(qs[mt], 16, 64); qs[mt] += __shfl_xor(qs[mt], 32, 64);
        ks[mt] += __shfl_xor(ks[mt], 16, 64); ks[mt] += __shfl_xor(ks[mt], 32, 64);
    }
    CFENCE();
    // ---- write normalized q,k into LDS (frees aq/ak) ----
#pragma unroll
    for (int mt = 0; mt < 4; ++mt) {
        float qr = sc / fmaxf(sqrtf(qs[mt]), 1e-12f);
        float kr = 1.f / fmaxf(sqrtf(ks[mt]), 1e-12f);
        int tok = mt * 16 + l15;
#pragma unroll
        for (int i = 0; i < 2; ++i) {
            shortx4 oq, ok;
#pragma unroll
            for (int r = 0; r < 4; ++r) {
                oq[r] = f2bf(aq[i][mt][r] * qr);
                ok[r] = f2bf(ak[i][mt][r] * kr);
            }
            *(shortx4*)&qn[tok * 34 + i * 16 + quad * 4] = oq;
            *(shortx4*)&kn[tok * 34 + i * 16 + quad * 4] = ok;
        }
    }
    CFENCE();
    // ======== V GEMM: af from LDS (cheap), 8 MFMA per kt, peak ~64 regs ========
    floatx4 av[2][4];
#pragma unroll
    for (int i = 0; i < 2; ++i)
#pragma unroll
        for (int mt = 0; mt < 4; ++mt) av[i][mt] = (floatx4){0.f, 0.f, 0.f, 0.f};
#pragma unroll
    for (int kt = 0; kt < 8; ++kt) {
        shortx8 af[4];
#pragma unroll
        for (int mt = 0; mt < 4; ++mt)
            af[mt] = *(const shortx8*)&xtile[(mt * 8 + kt) * 512 + lane * 8];
        shortx8 wvf[2];
#pragma unroll
        for (int i = 0; i < 2; ++i) {
            int n16 = 2 * h + i;
            wvf[i] = *(const shortx8*)(wf + (size_t)((32 + n16) * 8 + kt) * 512 + lane * 8);
        }
#pragma unroll
        for (int i = 0; i < 2; ++i)
#pragma unroll
            for (int mt = 0; mt < 4; ++mt)
                av[i][mt] = __builtin_amdgcn_mfma_f32_16x16x32_bf16(wvf[i], af[mt], av[i][mt], 0, 0, 0);
    }
    // ---- bias + write transposed v into LDS ----
#pragma unroll
    for (int i = 0; i < 2; ++i) {
        float bvv[4];
#pragma unroll
        for (int r = 0; r < 4; ++r) bvv[r] = bv[h * 32 + i * 16 + quad * 4 + r];
#pragma unroll
        for (int mt = 0; mt < 4; ++mt) {
            int tok = mt * 16 + l15;
#pragma unroll
            for (int r = 0; r < 4; ++r)
                vt[(i * 16 + quad * 4 + r) * 68 + tok] = f2bf(av[i][mt][r] + bvv[r]);
        }
    }
    CFENCE();
    // ======== QK^T ========
    shortx8 aqf[4], bkf[4];
#pragma unroll
    for (int mt = 0; mt < 4; ++mt)
        aqf[mt] = *(const shortx8*)&qn[(mt * 16 + l15) * 34 + quad * 8];
#pragma unroll
    for (int nt = 0; nt < 4; ++nt)
        bkf[nt] = *(const shortx8*)&kn[(nt * 16 + l15) * 34 + quad * 8];
    floatx4 S[4][4];
#pragma unroll
    for (int mt = 0; mt < 4; ++mt)
#pragma unroll
        for (int nt = 0; nt < 4; ++nt) {
            floatx4 z = {0.f, 0.f, 0.f, 0.f};
            S[mt][nt] = __builtin_amdgcn_mfma_f32_16x16x32_bf16(aqf[mt], bkf[nt], z, 0, 0, 0);
        }
    // ======== softmax (bias via transposed float4 loads) ========
    const float* bh = bias_t + (h << 12);
    float bound = sc + 16.5f;
    int jid[4];
    if (need_mask) {
#pragma unroll
        for (int nt = 0; nt < 4; ++nt) jid[nt] = regid(nt * 16 + l15, wi, wj);
    }
    float rs[4][4];
#pragma unroll
    for (int mt = 0; mt < 4; ++mt) {
        float4 b4[4];
#pragma unroll
        for (int nt = 0; nt < 4; ++nt)
            b4[nt] = *(const float4*)&bh[(nt * 16 + l15) * 64 + mt * 16 + quad * 4];
#pragma unroll
        for (int reg = 0; reg < 4; ++reg) {
            int i = mt * 16 + quad * 4 + reg;
            int iid = need_mask ? regid(i, wi, wj) : 0;
            float rowsum = 0.f;
#pragma unroll
            for (int nt = 0; nt < 4; ++nt) {
                float bb = (reg == 0) ? b4[nt].x : (reg == 1) ? b4[nt].y
                         : (reg == 2) ? b4[nt].z : b4[nt].w;
                float v = S[mt][nt][reg] + bb;
                if (need_mask && iid != jid[nt]) v -= 100.f;
                float pe = __expf(v - bound);
                S[mt][nt][reg] = pe;
                rowsum += pe;
            }
            rowsum += __shfl_xor(rowsum, 1, 64);
            rowsum += __shfl_xor(rowsum, 2, 64);
            rowsum += __shfl_xor(rowsum, 4, 64);
            rowsum += __shfl_xor(rowsum, 8, 64);
            rs[mt][reg] = 1.f / rowsum;
        }
    }
    CFENCE();
    // ---- P into LDS (aliases qn+kn; frags already consumed) ----
#pragma unroll
    for (int mt = 0; mt < 4; ++mt)
#pragma unroll
        for (int nt = 0; nt < 4; ++nt)
#pragma unroll
            for (int reg = 0; reg < 4; ++reg)
                P[(mt * 16 + quad * 4 + reg) * 68 + nt * 16 + l15] = f2bf(S[mt][nt][reg]);
    CFENCE();
    // ======== PV ========
    floatx4 O[4][2];
#pragma unroll
    for (int mt = 0; mt < 4; ++mt)
#pragma unroll
        for (int nt = 0; nt < 2; ++nt) O[mt][nt] = (floatx4){0.f, 0.f, 0.f, 0.f};
#pragma unroll
    for (int ks2 = 0; ks2 < 2; ++ks2) {
        shortx8 pa[4], vb[2];
#pragma unroll
        for (int mt = 0; mt < 4; ++mt)
            pa[mt] = *(const shortx8*)&P[(mt * 16 + l15) * 68 + ks2 * 32 + quad * 8];
#pragma unroll
        for (int nt = 0; nt < 2; ++nt)
            vb[nt] = *(const shortx8*)&vt[(nt * 16 + l15) * 68 + ks2 * 32 + quad * 8];
#pragma unroll
        for (int mt = 0; mt < 4; ++mt)
#pragma unroll
            for (int nt = 0; nt < 2; ++nt)
                O[mt][nt] = __builtin_amdgcn_mfma_f32_16x16x32_bf16(pa[mt], vb[nt], O[mt][nt], 0, 0, 0);
    }
    // ---- scale + pack to bf16 (light: 16 regs) ----
    shortx4 Obf[4][2];
#pragma unroll
    for (int mt = 0; mt < 4; ++mt)
#pragma unroll
        for (int nt = 0; nt < 2; ++nt) {
            shortx4 s;
#pragma unroll
            for (int reg = 0; reg < 4; ++reg)
                s[reg] = f2bf(O[mt][nt][reg] * rs[mt][reg]);
            Obf[mt][nt] = s;
        }

    // ---- all waves done: xtile + scratch dead; gather Ao[64][264], O-proj ----
    __syncthreads();
    short* Ao = lds;
#pragma unroll
    for (int mt = 0; mt < 4; ++mt)
#pragma unroll
        for (int nt = 0; nt < 2; ++nt)
#pragma unroll
            for (int reg = 0; reg < 4; ++reg)
                Ao[(mt * 16 + quad * 4 + reg) * 264 + h * 32 + nt * 16 + l15] =
                    Obf[mt][nt][reg];
    __syncthreads();

    int pix[4];
#pragma unroll
    for (int mt = 0; mt < 4; ++mt) pix[mt] = row2pix(win * 64 + mt * 16 + l15);

    floatx4 acc2[2][4];   // [nt][mt], wave covers n16 = wid*2 + nt
#pragma unroll
    for (int nt = 0; nt < 2; ++nt)
#pragma unroll
        for (int mt = 0; mt < 4; ++mt) acc2[nt][mt] = (floatx4){0.f, 0.f, 0.f, 0.f};
#pragma unroll
    for (int kt = 0; kt < 8; ++kt) {
        shortx8 bw[2], af2[4];
#pragma unroll
        for (int nt = 0; nt < 2; ++nt)
            bw[nt] = *(const shortx8*)(wof + (size_t)((wid * 2 + nt) * 8 + kt) * 512 + lane * 8);
#pragma unroll
        for (int mt = 0; mt < 4; ++mt)
            af2[mt] = *(const shortx8*)&Ao[(mt * 16 + l15) * 264 + kt * 32 + quad * 8];
#pragma unroll
        for (int nt = 0; nt < 2; ++nt)
#pragma unroll
            for (int mt = 0; mt < 4; ++mt)
                acc2[nt][mt] = __builtin_amdgcn_mfma_f32_16x16x32_bf16(bw[nt], af2[mt], acc2[nt][mt], 0, 0, 0);
    }
#pragma unroll
    for (int nt = 0; nt < 2; ++nt) {
        int nb = (wid * 2 + nt) * 16 + quad * 4;
        float bs[4];
#pragma unroll
        for (int reg = 0; reg < 4; ++reg) bs[reg] = bo[nb + reg];
#pragma unroll
        for (int mt = 0; mt < 4; ++mt) {
            float4 o;
            o.x = acc2[nt][mt][0] + bs[0];
            o.y = acc2[nt][mt][1] + bs[1];
            o.z = acc2[nt][mt][2] + bs[2];
            o.w = acc2[nt][mt][3] + bs[3];
            *(float4*)(out + (size_t)pix[mt] * 256 + nb) = o;
        }
    }
}

// ---------------- launch ----------------
extern "C" void kernel_launch(void* const* d_in, const int* in_sizes, int n_in,
                              void* d_out, int out_size, void* d_ws, size_t ws_size,
                              hipStream_t stream) {
    const float* x  = (const float*)d_in[0];
    const float* Wq = (const float*)d_in[1];
    const float* bq = (const float*)d_in[2];
    const float* Wk = (const float*)d_in[3];
    const float* bk = (const float*)d_in[4];
    const float* Wv = (const float*)d_in[5];
    const float* bv = (const float*)d_in[6];
    const float* Wo = (const float*)d_in[7];
    const float* bo = (const float*)d_in[8];
    const float* ls = (const float*)d_in[9];
    const float* w1 = (const float*)d_in[10];
    const float* b1 = (const float*)d_in[11];
    const float* w2 = (const float*)d_in[12];

    char* ws = (char*)d_ws;
    short* wqkv_f = (short*)(ws + 0);           //   393,216 B
    short* wo_f   = (short*)(ws + 393216);      //   131,072 B
    float* bias_t = (float*)(ws + 524288);      //   131,072 B
    float* scale  = (float*)(ws + 655360);      //        32 B
    float* b225g  = (float*)(ws + 786432);      //     7,200 B
    float* out    = (float*)d_out;

    hipLaunchKernelGGL(wtrans, dim3(128), dim3(256), 0, stream, Wq, Wk, Wv, Wo, wqkv_f, wo_f);
    hipLaunchKernelGGL(bias_mlp, dim3(225), dim3(256), 0, stream, ls, w1, b1, w2, b225g, scale);
    hipLaunchKernelGGL(bias_expand, dim3(128), dim3(256), 0, stream, b225g, bias_t);
    hipLaunchKernelGGL(swin_fused, dim3(1024), dim3(512), 0, stream,
                       x, wqkv_f, wo_f, bq, bk, bv, bo, bias_t, scale, out);
}

// Round 10
// 220.689 us; speedup vs baseline: 1.5481x; 1.0235x over previous
//
#include <hip/hip_runtime.h>
#include <hip/hip_bf16.h>

typedef float floatx4 __attribute__((ext_vector_type(4)));
typedef short shortx8 __attribute__((ext_vector_type(8)));
typedef short shortx4 __attribute__((ext_vector_type(4)));

#define CFENCE() asm volatile("" ::: "memory")

__device__ __forceinline__ float bf2f(short s) {
    union { unsigned u; float f; } cv;
    cv.u = ((unsigned)(unsigned short)s) << 16;
    return cv.f;
}
__device__ __forceinline__ short f2bf(float f) {
    union { float f; unsigned u; } cv; cv.f = f;
    unsigned r = (cv.u + 0x7fffu + ((cv.u >> 16) & 1u)) >> 16;
    return (short)r;
}

// ---------------- K0a: weights -> bf16 fragment-major layout ----------------
__global__ __launch_bounds__(256) void wtrans(const float* __restrict__ Wq,
                                              const float* __restrict__ Wk,
                                              const float* __restrict__ Wv,
                                              const float* __restrict__ Wo,
                                              short* __restrict__ wqkv_f,
                                              short* __restrict__ wo_f) {
    int gtid = blockIdx.x * 256 + threadIdx.x;
    int f = gtid >> 6, lane = gtid & 63;
    int quad = lane >> 4, l15 = lane & 15;
    if (f < 384) {
        int n16 = f >> 3, kt = f & 7;
        int n = n16 * 16 + l15, z = n >> 8, ncol = n & 255;
        const float* src = (z == 0) ? Wq : (z == 1) ? Wk : Wv;
        shortx8 s;
#pragma unroll
        for (int j = 0; j < 8; ++j)
            s[j] = f2bf(src[(size_t)(kt * 32 + quad * 8 + j) * 256 + ncol]);
        *(shortx8*)(wqkv_f + (size_t)f * 512 + lane * 8) = s;
    } else {
        int f2 = f - 384;
        int n16 = f2 >> 3, kt = f2 & 7;
        int n = n16 * 16 + l15;
        shortx8 s;
#pragma unroll
        for (int j = 0; j < 8; ++j)
            s[j] = f2bf(Wo[(size_t)(kt * 32 + quad * 8 + j) * 256 + n]);
        *(shortx8*)(wo_f + (size_t)f2 * 512 + lane * 8) = s;
    }
}

// ---------------- K0b: CPB MLP ----------------
__device__ __forceinline__ float sgnlog(float x) {
    return copysignf(__log2f(fabsf(x) + 1.f) / 3.f, x);
}
__global__ __launch_bounds__(256) void bias_mlp(const float* __restrict__ ls,
                                                const float* __restrict__ w1,
                                                const float* __restrict__ b1,
                                                const float* __restrict__ w2,
                                                float* __restrict__ b225g,
                                                float* __restrict__ scaleOut) {
    int e = blockIdx.x;
    int tid = threadIdx.x, lane = tid & 63, wid = tid >> 6;
    if (e == 0 && tid < 8) scaleOut[tid] = expf(fminf(ls[tid], 4.6051701859880914f));
    int dh = e / 15 - 7, dw = e % 15 - 7;
    float t0 = sgnlog(8.f * (float)dh / 7.f);
    float t1 = sgnlog(8.f * (float)dw / 7.f);
    float acc[8];
#pragma unroll
    for (int j = 0; j < 8; ++j) acc[j] = 0.f;
#pragma unroll
    for (int s = 0; s < 2; ++s) {
        int hsm = tid + s * 256;
        float hid = fmaxf(0.f, t0 * w1[hsm] + t1 * w1[512 + hsm] + b1[hsm]);
#pragma unroll
        for (int j = 0; j < 8; ++j) acc[j] += hid * w2[hsm * 8 + j];
    }
#pragma unroll
    for (int off = 1; off < 64; off <<= 1)
#pragma unroll
        for (int j = 0; j < 8; ++j) acc[j] += __shfl_xor(acc[j], off, 64);
    __shared__ float red[4][8];
    if (lane == 0)
#pragma unroll
        for (int j = 0; j < 8; ++j) red[wid][j] = acc[j];
    __syncthreads();
    if (tid < 8)
        b225g[e * 8 + tid] = red[0][tid] + red[1][tid] + red[2][tid] + red[3][tid];
}

// ---------------- K0c: expand to per-head 64x64 bias, [h][i][j] (i=query row) ----------
__global__ __launch_bounds__(256) void bias_expand(const float* __restrict__ b225g,
                                                   float* __restrict__ bias8) {
    int f = blockIdx.x * 256 + threadIdx.x;
    int h = f >> 12, ij = f & 4095, i = ij >> 6, j = ij & 63;
    int dh = (i >> 3) - (j >> 3), dw = (i & 7) - (j & 7);
    int e = (dh + 7) * 15 + (dw + 7);
    float v = b225g[e * 8 + h];
    bias8[f] = 16.f / (1.f + expf(-v));
}

// token row -> pixel (roll by +4 both ways, same map fwd/bwd)
__device__ __forceinline__ int row2pix(int row) {
    int w = row >> 6, t = row & 63;
    int b = w >> 6, wi = (w >> 3) & 7, wj = w & 7;
    int hh = (wi * 8 + (t >> 3) + 4) & 63;
    int ww = (wj * 8 + (t & 7) + 4) & 63;
    return (b * 64 + hh) * 64 + ww;
}

__device__ __forceinline__ int regid(int t, int wi, int wj) {
    int a = (wi < 7) ? 0 : (((t >> 3) < 4) ? 1 : 2);
    int b = (wj < 7) ? 0 : (((t & 7) < 4) ? 1 : 2);
    return a * 3 + b;
}

// ---------------- Fused: QKV + attention + O-proj, one 512-thread block per window ----
// r9 skeleton + round-10 deltas:
//  (1) S^T swap: S^T = mfma(K,Q) -> softmax row (qtok) lies on l15; rowsum = in-thread
//      adds + 2 shfls (was 64 shfls); bias float4 from [h][i][j]; normalization folded
//      into P (16 shortx4 writes, was 64 scalar); O-scale deleted.
//  (2) xtile XOR swizzle: write slot (c4*16 + ((r&15)^seg)), read (lane^kt)*8 —
//      staging-write conflicts 8-way -> 2-way; reads stay conflict-free permutation.
//  (3) s_setprio(1) around the QK / V / O-proj MFMA bursts.
__global__ __launch_bounds__(512, 2) void swin_fused(const float* __restrict__ x,
                                                     const short* __restrict__ wf,
                                                     const short* __restrict__ wof,
                                                     const float* __restrict__ bq,
                                                     const float* __restrict__ bk_,
                                                     const float* __restrict__ bv,
                                                     const float* __restrict__ bo,
                                                     const float* __restrict__ bias8,
                                                     const float* __restrict__ scale,
                                                     float* __restrict__ out) {
    __shared__ __align__(16) short lds[68608];   // 137216 B
    int tid = threadIdx.x, lane = tid & 63, wid = tid >> 6;   // wid 0..7
    int quad = lane >> 4, l15 = lane & 15;
    int win = blockIdx.x;
    int wi = (win >> 3) & 7, wj = win & 7;
    bool need_mask = (wi == 7) || (wj == 7);

    short* xtile = lds;                       // 16384 shorts (32 KB), frag-major+swizzle
    short* qn = &lds[16384 + wid * 6528];     // [64][34]  (2176)
    short* kn = qn + 2176;                    // [64][34]  (2176)
    short* vt = qn + 4352;                    // [32][68]  (2176)
    short* P  = qn;                           // [64][68]  (4352) aliases qn+kn

    // ---- stage x -> xtile (fp32 -> bf16 frag-major, XOR-swizzled slots) ----
    {
        int r = tid >> 3, seg = tid & 7;      // token r, kt-segment seg
        const float* src = x + (size_t)row2pix(win * 64 + r) * 256 + seg * 32;
        short* fbase = &xtile[((r >> 4) * 8 + seg) * 512];
        int slo = (r & 15) ^ seg;             // swizzled low slot bits
#pragma unroll
        for (int c4 = 0; c4 < 4; ++c4) {
            float4 u0 = *(const float4*)(src + c4 * 8);
            float4 u1 = *(const float4*)(src + c4 * 8 + 4);
            shortx8 t;
            t[0] = f2bf(u0.x); t[1] = f2bf(u0.y); t[2] = f2bf(u0.z); t[3] = f2bf(u0.w);
            t[4] = f2bf(u1.x); t[5] = f2bf(u1.y); t[6] = f2bf(u1.z); t[7] = f2bf(u1.w);
            *(shortx8*)(fbase + (c4 * 16 + slo) * 8) = t;
        }
    }
    __syncthreads();

    int h = wid;
    float sc = scale[h];

    // ======== QK GEMM (C^T): af from swizzled xtile, 16 MFMA per kt ========
    floatx4 aq[2][4], ak[2][4];
#pragma unroll
    for (int i = 0; i < 2; ++i)
#pragma unroll
        for (int mt = 0; mt < 4; ++mt) {
            aq[i][mt] = (floatx4){0.f, 0.f, 0.f, 0.f};
            ak[i][mt] = (floatx4){0.f, 0.f, 0.f, 0.f};
        }
#pragma unroll
    for (int kt = 0; kt < 8; ++kt) {
        shortx8 af[4];
#pragma unroll
        for (int mt = 0; mt < 4; ++mt)
            af[mt] = *(const shortx8*)&xtile[(mt * 8 + kt) * 512 + (lane ^ kt) * 8];
        shortx8 wqf[2], wkf[2];
#pragma unroll
        for (int i = 0; i < 2; ++i) {
            int n16 = 2 * h + i;
            wqf[i] = *(const shortx8*)(wf + (size_t)((n16)*8 + kt) * 512 + lane * 8);
            wkf[i] = *(const shortx8*)(wf + (size_t)((16 + n16) * 8 + kt) * 512 + lane * 8);
        }
        __builtin_amdgcn_s_setprio(1);
#pragma unroll
        for (int i = 0; i < 2; ++i)
#pragma unroll
            for (int mt = 0; mt < 4; ++mt) {
                aq[i][mt] = __builtin_amdgcn_mfma_f32_16x16x32_bf16(wqf[i], af[mt], aq[i][mt], 0, 0, 0);
                ak[i][mt] = __builtin_amdgcn_mfma_f32_16x16x32_bf16(wkf[i], af[mt], ak[i][mt], 0, 0, 0);
            }
        __builtin_amdgcn_s_setprio(0);
    }
    // ---- bias + cosine norms (token = col; sum over quads via shfl) ----
    float qs[4], ks[4];
#pragma unroll
    for (int mt = 0; mt < 4; ++mt) { qs[mt] = 0.f; ks[mt] = 0.f; }
#pragma unroll
    for (int i = 0; i < 2; ++i) {
        float bqv[4], bkv[4];
#pragma unroll
        for (int r = 0; r < 4; ++r) {
            int d = i * 16 + quad * 4 + r;
            bqv[r] = bq[h * 32 + d];
            bkv[r] = bk_[h * 32 + d];
        }
#pragma unroll
        for (int mt = 0; mt < 4; ++mt)
#pragma unroll
            for (int r = 0; r < 4; ++r) {
                float qv = aq[i][mt][r] + bqv[r]; aq[i][mt][r] = qv; qs[mt] += qv * qv;
                float kv = ak[i][mt][r] + bkv[r]; ak[i][mt][r] = kv; ks[mt] += kv * kv;
            }
    }
#pragma unroll
    for (int mt = 0; mt < 4; ++mt) {
        qs[mt] += __shfl_xor(qs[mt], 16, 64); qs[mt] += __shfl_xor(qs[mt], 32, 64);
        ks[mt] += __shfl_xor(ks[mt], 16, 64); ks[mt] += __shfl_xor(ks[mt], 32, 64);
    }
    CFENCE();
    // ---- write normalized q,k into LDS (frees aq/ak) ----
#pragma unroll
    for (int mt = 0; mt < 4; ++mt) {
        float qr = sc / fmaxf(sqrtf(qs[mt]), 1e-12f);
        float kr = 1.f / fmaxf(sqrtf(ks[mt]), 1e-12f);
        int tok = mt * 16 + l15;
#pragma unroll
        for (int i = 0; i < 2; ++i) {
            shortx4 oq, ok;
#pragma unroll
            for (int r = 0; r < 4; ++r) {
                oq[r] = f2bf(aq[i][mt][r] * qr);
                ok[r] = f2bf(ak[i][mt][r] * kr);
            }
            *(shortx4*)&qn[tok * 34 + i * 16 + quad * 4] = oq;
            *(shortx4*)&kn[tok * 34 + i * 16 + quad * 4] = ok;
        }
    }
    CFENCE();
    // ======== V GEMM: af from swizzled xtile, 8 MFMA per kt ========
    floatx4 av[2][4];
#pragma unroll
    for (int i = 0; i < 2; ++i)
#pragma unroll
        for (int mt = 0; mt < 4; ++mt) av[i][mt] = (floatx4){0.f, 0.f, 0.f, 0.f};
#pragma unroll
    for (int kt = 0; kt < 8; ++kt) {
        shortx8 af[4];
#pragma unroll
        for (int mt = 0; mt < 4; ++mt)
            af[mt] = *(const shortx8*)&xtile[(mt * 8 + kt) * 512 + (lane ^ kt) * 8];
        shortx8 wvf[2];
#pragma unroll
        for (int i = 0; i < 2; ++i) {
            int n16 = 2 * h + i;
            wvf[i] = *(const shortx8*)(wf + (size_t)((32 + n16) * 8 + kt) * 512 + lane * 8);
        }
        __builtin_amdgcn_s_setprio(1);
#pragma unroll
        for (int i = 0; i < 2; ++i)
#pragma unroll
            for (int mt = 0; mt < 4; ++mt)
                av[i][mt] = __builtin_amdgcn_mfma_f32_16x16x32_bf16(wvf[i], af[mt], av[i][mt], 0, 0, 0);
        __builtin_amdgcn_s_setprio(0);
    }
    // ---- bias + write transposed v into LDS ----
#pragma unroll
    for (int i = 0; i < 2; ++i) {
        float bvv[4];
#pragma unroll
        for (int r = 0; r < 4; ++r) bvv[r] = bv[h * 32 + i * 16 + quad * 4 + r];
#pragma unroll
        for (int mt = 0; mt < 4; ++mt) {
            int tok = mt * 16 + l15;
#pragma unroll
            for (int r = 0; r < 4; ++r)
                vt[(i * 16 + quad * 4 + r) * 68 + tok] = f2bf(av[i][mt][r] + bvv[r]);
        }
    }
    CFENCE();
    // ======== QK^T, swapped: S^T[ktok][qtok] = mfma(K-frag, Q-frag) ========
    shortx8 aqf[4], bkf[4];
#pragma unroll
    for (int mt = 0; mt < 4; ++mt)
        aqf[mt] = *(const shortx8*)&qn[(mt * 16 + l15) * 34 + quad * 8];
#pragma unroll
    for (int nt = 0; nt < 4; ++nt)
        bkf[nt] = *(const shortx8*)&kn[(nt * 16 + l15) * 34 + quad * 8];
    floatx4 S[4][4];   // S[mt][nt] = S^T tile: rows ktok = mt*16+quad*4+reg, cols qtok = nt*16+l15
#pragma unroll
    for (int mt = 0; mt < 4; ++mt)
#pragma unroll
        for (int nt = 0; nt < 4; ++nt) {
            floatx4 z = {0.f, 0.f, 0.f, 0.f};
            S[mt][nt] = __builtin_amdgcn_mfma_f32_16x16x32_bf16(bkf[mt], aqf[nt], z, 0, 0, 0);
        }
    // ======== softmax over ktok (in-thread + 2 shfls per qtok) ========
    const float* bh = bias8 + (h << 12);
    float bound = sc + 16.5f;
    int jd[4][4];
    if (need_mask) {
#pragma unroll
        for (int mt = 0; mt < 4; ++mt)
#pragma unroll
            for (int reg = 0; reg < 4; ++reg)
                jd[mt][reg] = regid(mt * 16 + quad * 4 + reg, wi, wj);
    }
    float rsinv[4];
#pragma unroll
    for (int nt = 0; nt < 4; ++nt) {
        int qt = nt * 16 + l15;
        int iid = need_mask ? regid(qt, wi, wj) : 0;
        const float* brow = bh + qt * 64;
        float rowsum = 0.f;
#pragma unroll
        for (int mt = 0; mt < 4; ++mt) {
            float4 b4 = *(const float4*)&brow[mt * 16 + quad * 4];
#pragma unroll
            for (int reg = 0; reg < 4; ++reg) {
                float bb = (reg == 0) ? b4.x : (reg == 1) ? b4.y : (reg == 2) ? b4.z : b4.w;
                float v = S[mt][nt][reg] + bb;
                if (need_mask && iid != jd[mt][reg]) v -= 100.f;
                float pe = __expf(v - bound);
                S[mt][nt][reg] = pe;
                rowsum += pe;
            }
        }
        rowsum += __shfl_xor(rowsum, 16, 64);
        rowsum += __shfl_xor(rowsum, 32, 64);
        rsinv[nt] = 1.f / rowsum;
    }
    CFENCE();
    // ---- P into LDS (qtok-major, normalization folded in; 16 shortx4 writes) ----
#pragma unroll
    for (int nt = 0; nt < 4; ++nt)
#pragma unroll
        for (int mt = 0; mt < 4; ++mt) {
            shortx4 s;
#pragma unroll
            for (int reg = 0; reg < 4; ++reg)
                s[reg] = f2bf(S[mt][nt][reg] * rsinv[nt]);
            *(shortx4*)&P[(nt * 16 + l15) * 68 + mt * 16 + quad * 4] = s;
        }
    CFENCE();
    // ======== PV (P pre-normalized) ========
    floatx4 O[4][2];
#pragma unroll
    for (int mt = 0; mt < 4; ++mt)
#pragma unroll
        for (int nt = 0; nt < 2; ++nt) O[mt][nt] = (floatx4){0.f, 0.f, 0.f, 0.f};
#pragma unroll
    for (int ks2 = 0; ks2 < 2; ++ks2) {
        shortx8 pa[4], vb[2];
#pragma unroll
        for (int mt = 0; mt < 4; ++mt)
            pa[mt] = *(const shortx8*)&P[(mt * 16 + l15) * 68 + ks2 * 32 + quad * 8];
#pragma unroll
        for (int nt = 0; nt < 2; ++nt)
            vb[nt] = *(const shortx8*)&vt[(nt * 16 + l15) * 68 + ks2 * 32 + quad * 8];
#pragma unroll
        for (int mt = 0; mt < 4; ++mt)
#pragma unroll
            for (int nt = 0; nt < 2; ++nt)
                O[mt][nt] = __builtin_amdgcn_mfma_f32_16x16x32_bf16(pa[mt], vb[nt], O[mt][nt], 0, 0, 0);
    }
    // ---- pack to bf16 (already normalized) ----
    shortx4 Obf[4][2];
#pragma unroll
    for (int mt = 0; mt < 4; ++mt)
#pragma unroll
        for (int nt = 0; nt < 2; ++nt) {
            shortx4 s;
#pragma unroll
            for (int reg = 0; reg < 4; ++reg)
                s[reg] = f2bf(O[mt][nt][reg]);
            Obf[mt][nt] = s;
        }

    // ---- all waves done: xtile + scratch dead; gather Ao[64][264], O-proj ----
    __syncthreads();
    short* Ao = lds;
#pragma unroll
    for (int mt = 0; mt < 4; ++mt)
#pragma unroll
        for (int nt = 0; nt < 2; ++nt)
#pragma unroll
            for (int reg = 0; reg < 4; ++reg)
                Ao[(mt * 16 + quad * 4 + reg) * 264 + h * 32 + nt * 16 + l15] =
                    Obf[mt][nt][reg];
    __syncthreads();

    int pix[4];
#pragma unroll
    for (int mt = 0; mt < 4; ++mt) pix[mt] = row2pix(win * 64 + mt * 16 + l15);

    floatx4 acc2[2][4];   // [nt][mt], wave covers n16 = wid*2 + nt
#pragma unroll
    for (int nt = 0; nt < 2; ++nt)
#pragma unroll
        for (int mt = 0; mt < 4; ++mt) acc2[nt][mt] = (floatx4){0.f, 0.f, 0.f, 0.f};
#pragma unroll
    for (int kt = 0; kt < 8; ++kt) {
        shortx8 bw[2], af2[4];
#pragma unroll
        for (int nt = 0; nt < 2; ++nt)
            bw[nt] = *(const shortx8*)(wof + (size_t)((wid * 2 + nt) * 8 + kt) * 512 + lane * 8);
#pragma unroll
        for (int mt = 0; mt < 4; ++mt)
            af2[mt] = *(const shortx8*)&Ao[(mt * 16 + l15) * 264 + kt * 32 + quad * 8];
        __builtin_amdgcn_s_setprio(1);
#pragma unroll
        for (int nt = 0; nt < 2; ++nt)
#pragma unroll
            for (int mt = 0; mt < 4; ++mt)
                acc2[nt][mt] = __builtin_amdgcn_mfma_f32_16x16x32_bf16(bw[nt], af2[mt], acc2[nt][mt], 0, 0, 0);
        __builtin_amdgcn_s_setprio(0);
    }
#pragma unroll
    for (int nt = 0; nt < 2; ++nt) {
        int nb = (wid * 2 + nt) * 16 + quad * 4;
        float bs[4];
#pragma unroll
        for (int reg = 0; reg < 4; ++reg) bs[reg] = bo[nb + reg];
#pragma unroll
        for (int mt = 0; mt < 4; ++mt) {
            float4 o;
            o.x = acc2[nt][mt][0] + bs[0];
            o.y = acc2[nt][mt][1] + bs[1];
            o.z = acc2[nt][mt][2] + bs[2];
            o.w = acc2[nt][mt][3] + bs[3];
            *(float4*)(out + (size_t)pix[mt] * 256 + nb) = o;
        }
    }
}

// ---------------- launch ----------------
extern "C" void kernel_launch(void* const* d_in, const int* in_sizes, int n_in,
                              void* d_out, int out_size, void* d_ws, size_t ws_size,
                              hipStream_t stream) {
    const float* x  = (const float*)d_in[0];
    const float* Wq = (const float*)d_in[1];
    const float* bq = (const float*)d_in[2];
    const float* Wk = (const float*)d_in[3];
    const float* bk = (const float*)d_in[4];
    const float* Wv = (const float*)d_in[5];
    const float* bv = (const float*)d_in[6];
    const float* Wo = (const float*)d_in[7];
    const float* bo = (const float*)d_in[8];
    const float* ls = (const float*)d_in[9];
    const float* w1 = (const float*)d_in[10];
    const float* b1 = (const float*)d_in[11];
    const float* w2 = (const float*)d_in[12];

    char* ws = (char*)d_ws;
    short* wqkv_f = (short*)(ws + 0);           //   393,216 B
    short* wo_f   = (short*)(ws + 393216);      //   131,072 B
    float* bias8  = (float*)(ws + 524288);      //   131,072 B
    float* scale  = (float*)(ws + 655360);      //        32 B
    float* b225g  = (float*)(ws + 786432);      //     7,200 B
    float* out    = (float*)d_out;

    hipLaunchKernelGGL(wtrans, dim3(128), dim3(256), 0, stream, Wq, Wk, Wv, Wo, wqkv_f, wo_f);
    hipLaunchKernelGGL(bias_mlp, dim3(225), dim3(256), 0, stream, ls, w1, b1, w2, b225g, scale);
    hipLaunchKernelGGL(bias_expand, dim3(128), dim3(256), 0, stream, b225g, bias8);
    hipLaunchKernelGGL(swin_fused, dim3(1024), dim3(512), 0, stream,
                       x, wqkv_f, wo_f, bq, bk, bv, bo, bias8, scale, out);
}

// Round 11
// 219.053 us; speedup vs baseline: 1.5596x; 1.0075x over previous
//
#include <hip/hip_runtime.h>
#include <hip/hip_bf16.h>

typedef float floatx4 __attribute__((ext_vector_type(4)));
typedef short shortx8 __attribute__((ext_vector_type(8)));
typedef short shortx4 __attribute__((ext_vector_type(4)));

#define CFENCE() asm volatile("" ::: "memory")

__device__ __forceinline__ float bf2f(short s) {
    union { unsigned u; float f; } cv;
    cv.u = ((unsigned)(unsigned short)s) << 16;
    return cv.f;
}
__device__ __forceinline__ short f2bf(float f) {
    union { float f; unsigned u; } cv; cv.f = f;
    unsigned r = (cv.u + 0x7fffu + ((cv.u >> 16) & 1u)) >> 16;
    return (short)r;
}

// ---------------- K0a: weights -> bf16 fragment-major layout ----------------
__global__ __launch_bounds__(256) void wtrans(const float* __restrict__ Wq,
                                              const float* __restrict__ Wk,
                                              const float* __restrict__ Wv,
                                              const float* __restrict__ Wo,
                                              short* __restrict__ wqkv_f,
                                              short* __restrict__ wo_f) {
    int gtid = blockIdx.x * 256 + threadIdx.x;
    int f = gtid >> 6, lane = gtid & 63;
    int quad = lane >> 4, l15 = lane & 15;
    if (f < 384) {
        int n16 = f >> 3, kt = f & 7;
        int n = n16 * 16 + l15, z = n >> 8, ncol = n & 255;
        const float* src = (z == 0) ? Wq : (z == 1) ? Wk : Wv;
        shortx8 s;
#pragma unroll
        for (int j = 0; j < 8; ++j)
            s[j] = f2bf(src[(size_t)(kt * 32 + quad * 8 + j) * 256 + ncol]);
        *(shortx8*)(wqkv_f + (size_t)f * 512 + lane * 8) = s;
    } else {
        int f2 = f - 384;
        int n16 = f2 >> 3, kt = f2 & 7;
        int n = n16 * 16 + l15;
        shortx8 s;
#pragma unroll
        for (int j = 0; j < 8; ++j)
            s[j] = f2bf(Wo[(size_t)(kt * 32 + quad * 8 + j) * 256 + n]);
        *(shortx8*)(wo_f + (size_t)f2 * 512 + lane * 8) = s;
    }
}

// ---------------- K0b: CPB MLP ----------------
__device__ __forceinline__ float sgnlog(float x) {
    return copysignf(__log2f(fabsf(x) + 1.f) / 3.f, x);
}
__global__ __launch_bounds__(256) void bias_mlp(const float* __restrict__ ls,
                                                const float* __restrict__ w1,
                                                const float* __restrict__ b1,
                                                const float* __restrict__ w2,
                                                float* __restrict__ b225g,
                                                float* __restrict__ scaleOut) {
    int e = blockIdx.x;
    int tid = threadIdx.x, lane = tid & 63, wid = tid >> 6;
    if (e == 0 && tid < 8) scaleOut[tid] = expf(fminf(ls[tid], 4.6051701859880914f));
    int dh = e / 15 - 7, dw = e % 15 - 7;
    float t0 = sgnlog(8.f * (float)dh / 7.f);
    float t1 = sgnlog(8.f * (float)dw / 7.f);
    float acc[8];
#pragma unroll
    for (int j = 0; j < 8; ++j) acc[j] = 0.f;
#pragma unroll
    for (int s = 0; s < 2; ++s) {
        int hsm = tid + s * 256;
        float hid = fmaxf(0.f, t0 * w1[hsm] + t1 * w1[512 + hsm] + b1[hsm]);
#pragma unroll
        for (int j = 0; j < 8; ++j) acc[j] += hid * w2[hsm * 8 + j];
    }
#pragma unroll
    for (int off = 1; off < 64; off <<= 1)
#pragma unroll
        for (int j = 0; j < 8; ++j) acc[j] += __shfl_xor(acc[j], off, 64);
    __shared__ float red[4][8];
    if (lane == 0)
#pragma unroll
        for (int j = 0; j < 8; ++j) red[wid][j] = acc[j];
    __syncthreads();
    if (tid < 8)
        b225g[e * 8 + tid] = red[0][tid] + red[1][tid] + red[2][tid] + red[3][tid];
}

// ---------------- K0c: expand to per-head 64x64 bias, [h][i][j] (i=query row) ----------
__global__ __launch_bounds__(256) void bias_expand(const float* __restrict__ b225g,
                                                   float* __restrict__ bias8) {
    int f = blockIdx.x * 256 + threadIdx.x;
    int h = f >> 12, ij = f & 4095, i = ij >> 6, j = ij & 63;
    int dh = (i >> 3) - (j >> 3), dw = (i & 7) - (j & 7);
    int e = (dh + 7) * 15 + (dw + 7);
    float v = b225g[e * 8 + h];
    bias8[f] = 16.f / (1.f + expf(-v));
}

// token row -> pixel (roll by +4 both ways, same map fwd/bwd)
__device__ __forceinline__ int row2pix(int row) {
    int w = row >> 6, t = row & 63;
    int b = w >> 6, wi = (w >> 3) & 7, wj = w & 7;
    int hh = (wi * 8 + (t >> 3) + 4) & 63;
    int ww = (wj * 8 + (t & 7) + 4) & 63;
    return (b * 64 + hh) * 64 + ww;
}

__device__ __forceinline__ int regid(int t, int wi, int wj) {
    int a = (wi < 7) ? 0 : (((t >> 3) < 4) ? 1 : 2);
    int b = (wj < 7) ? 0 : (((t & 7) < 4) ? 1 : 2);
    return a * 3 + b;
}

// ---------------- Fused: QKV + attention + O-proj, one 512-thread block per window ----
// r10 skeleton + round-11 deltas:
//  (1) launch_bounds(512) [no min-waves]: VGPR cap 128 -> 256. LDS (137KB) already pins
//      occupancy at 1 block = 8 waves/CU, so the extra registers are free — lets the
//      compiler software-pipeline the kt loop (r10: VGPR 88 of 128, latency-bound).
//  (2) single-phase QKV (24 MFMA/kt): halves xtile passes, 2x MFMA per global load.
//      Peak ~150 live regs — spilled at cap 128 (r2/r3), clean at 256.
//  Kept: S^T softmax, XOR-swizzled xtile, setprio, strides 34/68 (conflicts ~1M = benign).
__global__ __launch_bounds__(512) void swin_fused(const float* __restrict__ x,
                                                  const short* __restrict__ wf,
                                                  const short* __restrict__ wof,
                                                  const float* __restrict__ bq,
                                                  const float* __restrict__ bk_,
                                                  const float* __restrict__ bv,
                                                  const float* __restrict__ bo,
                                                  const float* __restrict__ bias8,
                                                  const float* __restrict__ scale,
                                                  float* __restrict__ out) {
    __shared__ __align__(16) short lds[68608];   // 137216 B
    int tid = threadIdx.x, lane = tid & 63, wid = tid >> 6;   // wid 0..7
    int quad = lane >> 4, l15 = lane & 15;
    int win = blockIdx.x;
    int wi = (win >> 3) & 7, wj = win & 7;
    bool need_mask = (wi == 7) || (wj == 7);

    short* xtile = lds;                       // 16384 shorts (32 KB), frag-major+swizzle
    short* qn = &lds[16384 + wid * 6528];     // [64][34]  (2176)
    short* kn = qn + 2176;                    // [64][34]  (2176)
    short* vt = qn + 4352;                    // [32][68]  (2176)
    short* P  = qn;                           // [64][68]  (4352) aliases qn+kn

    // ---- stage x -> xtile (fp32 -> bf16 frag-major, XOR-swizzled slots) ----
    {
        int r = tid >> 3, seg = tid & 7;      // token r, kt-segment seg
        const float* src = x + (size_t)row2pix(win * 64 + r) * 256 + seg * 32;
        short* fbase = &xtile[((r >> 4) * 8 + seg) * 512];
        int slo = (r & 15) ^ seg;             // swizzled low slot bits
#pragma unroll
        for (int c4 = 0; c4 < 4; ++c4) {
            float4 u0 = *(const float4*)(src + c4 * 8);
            float4 u1 = *(const float4*)(src + c4 * 8 + 4);
            shortx8 t;
            t[0] = f2bf(u0.x); t[1] = f2bf(u0.y); t[2] = f2bf(u0.z); t[3] = f2bf(u0.w);
            t[4] = f2bf(u1.x); t[5] = f2bf(u1.y); t[6] = f2bf(u1.z); t[7] = f2bf(u1.w);
            *(shortx8*)(fbase + (c4 * 16 + slo) * 8) = t;
        }
    }
    __syncthreads();

    int h = wid;
    float sc = scale[h];

    // ======== QKV GEMM (C^T, single phase): 24 MFMA per kt ========
    floatx4 aq[2][4], ak[2][4], av[2][4];
#pragma unroll
    for (int i = 0; i < 2; ++i)
#pragma unroll
        for (int mt = 0; mt < 4; ++mt) {
            aq[i][mt] = (floatx4){0.f, 0.f, 0.f, 0.f};
            ak[i][mt] = (floatx4){0.f, 0.f, 0.f, 0.f};
            av[i][mt] = (floatx4){0.f, 0.f, 0.f, 0.f};
        }
#pragma unroll
    for (int kt = 0; kt < 8; ++kt) {
        shortx8 af[4];
#pragma unroll
        for (int mt = 0; mt < 4; ++mt)
            af[mt] = *(const shortx8*)&xtile[(mt * 8 + kt) * 512 + (lane ^ kt) * 8];
        shortx8 wqf[2], wkf[2], wvf[2];
#pragma unroll
        for (int i = 0; i < 2; ++i) {
            int n16 = 2 * h + i;
            wqf[i] = *(const shortx8*)(wf + (size_t)((n16)*8 + kt) * 512 + lane * 8);
            wkf[i] = *(const shortx8*)(wf + (size_t)((16 + n16) * 8 + kt) * 512 + lane * 8);
            wvf[i] = *(const shortx8*)(wf + (size_t)((32 + n16) * 8 + kt) * 512 + lane * 8);
        }
        __builtin_amdgcn_s_setprio(1);
#pragma unroll
        for (int i = 0; i < 2; ++i)
#pragma unroll
            for (int mt = 0; mt < 4; ++mt) {
                aq[i][mt] = __builtin_amdgcn_mfma_f32_16x16x32_bf16(wqf[i], af[mt], aq[i][mt], 0, 0, 0);
                ak[i][mt] = __builtin_amdgcn_mfma_f32_16x16x32_bf16(wkf[i], af[mt], ak[i][mt], 0, 0, 0);
                av[i][mt] = __builtin_amdgcn_mfma_f32_16x16x32_bf16(wvf[i], af[mt], av[i][mt], 0, 0, 0);
            }
        __builtin_amdgcn_s_setprio(0);
    }
    // ---- bias + cosine norms (token = col; sum over quads via shfl) ----
    float qs[4], ks[4];
#pragma unroll
    for (int mt = 0; mt < 4; ++mt) { qs[mt] = 0.f; ks[mt] = 0.f; }
#pragma unroll
    for (int i = 0; i < 2; ++i) {
        float bqv[4], bkv[4], bvv[4];
#pragma unroll
        for (int r = 0; r < 4; ++r) {
            int d = i * 16 + quad * 4 + r;
            bqv[r] = bq[h * 32 + d];
            bkv[r] = bk_[h * 32 + d];
            bvv[r] = bv[h * 32 + d];
        }
#pragma unroll
        for (int mt = 0; mt < 4; ++mt)
#pragma unroll
            for (int r = 0; r < 4; ++r) {
                float qv = aq[i][mt][r] + bqv[r]; aq[i][mt][r] = qv; qs[mt] += qv * qv;
                float kv = ak[i][mt][r] + bkv[r]; ak[i][mt][r] = kv; ks[mt] += kv * kv;
                av[i][mt][r] += bvv[r];
            }
    }
#pragma unroll
    for (int mt = 0; mt < 4; ++mt) {
        qs[mt] += __shfl_xor(qs[mt], 16, 64); qs[mt] += __shfl_xor(qs[mt], 32, 64);
        ks[mt] += __shfl_xor(ks[mt], 16, 64); ks[mt] += __shfl_xor(ks[mt], 32, 64);
    }
    CFENCE();
    // ---- write normalized q,k and transposed v into LDS ----
#pragma unroll
    for (int mt = 0; mt < 4; ++mt) {
        float qr = sc / fmaxf(sqrtf(qs[mt]), 1e-12f);
        float kr = 1.f / fmaxf(sqrtf(ks[mt]), 1e-12f);
        int tok = mt * 16 + l15;
#pragma unroll
        for (int i = 0; i < 2; ++i) {
            shortx4 oq, ok;
#pragma unroll
            for (int r = 0; r < 4; ++r) {
                oq[r] = f2bf(aq[i][mt][r] * qr);
                ok[r] = f2bf(ak[i][mt][r] * kr);
            }
            *(shortx4*)&qn[tok * 34 + i * 16 + quad * 4] = oq;
            *(shortx4*)&kn[tok * 34 + i * 16 + quad * 4] = ok;
#pragma unroll
            for (int r = 0; r < 4; ++r)
                vt[(i * 16 + quad * 4 + r) * 68 + tok] = f2bf(av[i][mt][r]);
        }
    }
    CFENCE();
    // ======== QK^T, swapped: S^T[ktok][qtok] = mfma(K-frag, Q-frag) ========
    shortx8 aqf[4], bkf[4];
#pragma unroll
    for (int mt = 0; mt < 4; ++mt)
        aqf[mt] = *(const shortx8*)&qn[(mt * 16 + l15) * 34 + quad * 8];
#pragma unroll
    for (int nt = 0; nt < 4; ++nt)
        bkf[nt] = *(const shortx8*)&kn[(nt * 16 + l15) * 34 + quad * 8];
    floatx4 S[4][4];   // S[mt][nt]: rows ktok = mt*16+quad*4+reg, cols qtok = nt*16+l15
#pragma unroll
    for (int mt = 0; mt < 4; ++mt)
#pragma unroll
        for (int nt = 0; nt < 4; ++nt) {
            floatx4 z = {0.f, 0.f, 0.f, 0.f};
            S[mt][nt] = __builtin_amdgcn_mfma_f32_16x16x32_bf16(bkf[mt], aqf[nt], z, 0, 0, 0);
        }
    // ======== softmax over ktok (in-thread + 2 shfls per qtok) ========
    const float* bh = bias8 + (h << 12);
    float bound = sc + 16.5f;
    int jd[4][4];
    if (need_mask) {
#pragma unroll
        for (int mt = 0; mt < 4; ++mt)
#pragma unroll
            for (int reg = 0; reg < 4; ++reg)
                jd[mt][reg] = regid(mt * 16 + quad * 4 + reg, wi, wj);
    }
    float rsinv[4];
#pragma unroll
    for (int nt = 0; nt < 4; ++nt) {
        int qt = nt * 16 + l15;
        int iid = need_mask ? regid(qt, wi, wj) : 0;
        const float* brow = bh + qt * 64;
        float rowsum = 0.f;
#pragma unroll
        for (int mt = 0; mt < 4; ++mt) {
            float4 b4 = *(const float4*)&brow[mt * 16 + quad * 4];
#pragma unroll
            for (int reg = 0; reg < 4; ++reg) {
                float bb = (reg == 0) ? b4.x : (reg == 1) ? b4.y : (reg == 2) ? b4.z : b4.w;
                float v = S[mt][nt][reg] + bb;
                if (need_mask && iid != jd[mt][reg]) v -= 100.f;
                float pe = __expf(v - bound);
                S[mt][nt][reg] = pe;
                rowsum += pe;
            }
        }
        rowsum += __shfl_xor(rowsum, 16, 64);
        rowsum += __shfl_xor(rowsum, 32, 64);
        rsinv[nt] = 1.f / rowsum;
    }
    CFENCE();
    // ---- P into LDS (qtok-major, normalization folded in; 16 shortx4 writes) ----
#pragma unroll
    for (int nt = 0; nt < 4; ++nt)
#pragma unroll
        for (int mt = 0; mt < 4; ++mt) {
            shortx4 s;
#pragma unroll
            for (int reg = 0; reg < 4; ++reg)
                s[reg] = f2bf(S[mt][nt][reg] * rsinv[nt]);
            *(shortx4*)&P[(nt * 16 + l15) * 68 + mt * 16 + quad * 4] = s;
        }
    CFENCE();
    // ======== PV (P pre-normalized) ========
    floatx4 O[4][2];
#pragma unroll
    for (int mt = 0; mt < 4; ++mt)
#pragma unroll
        for (int nt = 0; nt < 2; ++nt) O[mt][nt] = (floatx4){0.f, 0.f, 0.f, 0.f};
#pragma unroll
    for (int ks2 = 0; ks2 < 2; ++ks2) {
        shortx8 pa[4], vb[2];
#pragma unroll
        for (int mt = 0; mt < 4; ++mt)
            pa[mt] = *(const shortx8*)&P[(mt * 16 + l15) * 68 + ks2 * 32 + quad * 8];
#pragma unroll
        for (int nt = 0; nt < 2; ++nt)
            vb[nt] = *(const shortx8*)&vt[(nt * 16 + l15) * 68 + ks2 * 32 + quad * 8];
#pragma unroll
        for (int mt = 0; mt < 4; ++mt)
#pragma unroll
            for (int nt = 0; nt < 2; ++nt)
                O[mt][nt] = __builtin_amdgcn_mfma_f32_16x16x32_bf16(pa[mt], vb[nt], O[mt][nt], 0, 0, 0);
    }
    // ---- pack to bf16 (already normalized) ----
    shortx4 Obf[4][2];
#pragma unroll
    for (int mt = 0; mt < 4; ++mt)
#pragma unroll
        for (int nt = 0; nt < 2; ++nt) {
            shortx4 s;
#pragma unroll
            for (int reg = 0; reg < 4; ++reg)
                s[reg] = f2bf(O[mt][nt][reg]);
            Obf[mt][nt] = s;
        }

    // ---- all waves done: xtile + scratch dead; gather Ao[64][264], O-proj ----
    __syncthreads();
    short* Ao = lds;
#pragma unroll
    for (int mt = 0; mt < 4; ++mt)
#pragma unroll
        for (int nt = 0; nt < 2; ++nt)
#pragma unroll
            for (int reg = 0; reg < 4; ++reg)
                Ao[(mt * 16 + quad * 4 + reg) * 264 + h * 32 + nt * 16 + l15] =
                    Obf[mt][nt][reg];
    __syncthreads();

    int pix[4];
#pragma unroll
    for (int mt = 0; mt < 4; ++mt) pix[mt] = row2pix(win * 64 + mt * 16 + l15);

    floatx4 acc2[2][4];   // [nt][mt], wave covers n16 = wid*2 + nt
#pragma unroll
    for (int nt = 0; nt < 2; ++nt)
#pragma unroll
        for (int mt = 0; mt < 4; ++mt) acc2[nt][mt] = (floatx4){0.f, 0.f, 0.f, 0.f};
#pragma unroll
    for (int kt = 0; kt < 8; ++kt) {
        shortx8 bw[2], af2[4];
#pragma unroll
        for (int nt = 0; nt < 2; ++nt)
            bw[nt] = *(const shortx8*)(wof + (size_t)((wid * 2 + nt) * 8 + kt) * 512 + lane * 8);
#pragma unroll
        for (int mt = 0; mt < 4; ++mt)
            af2[mt] = *(const shortx8*)&Ao[(mt * 16 + l15) * 264 + kt * 32 + quad * 8];
        __builtin_amdgcn_s_setprio(1);
#pragma unroll
        for (int nt = 0; nt < 2; ++nt)
#pragma unroll
            for (int mt = 0; mt < 4; ++mt)
                acc2[nt][mt] = __builtin_amdgcn_mfma_f32_16x16x32_bf16(bw[nt], af2[mt], acc2[nt][mt], 0, 0, 0);
        __builtin_amdgcn_s_setprio(0);
    }
#pragma unroll
    for (int nt = 0; nt < 2; ++nt) {
        int nb = (wid * 2 + nt) * 16 + quad * 4;
        float bs[4];
#pragma unroll
        for (int reg = 0; reg < 4; ++reg) bs[reg] = bo[nb + reg];
#pragma unroll
        for (int mt = 0; mt < 4; ++mt) {
            float4 o;
            o.x = acc2[nt][mt][0] + bs[0];
            o.y = acc2[nt][mt][1] + bs[1];
            o.z = acc2[nt][mt][2] + bs[2];
            o.w = acc2[nt][mt][3] + bs[3];
            *(float4*)(out + (size_t)pix[mt] * 256 + nb) = o;
        }
    }
}

// ---------------- launch ----------------
extern "C" void kernel_launch(void* const* d_in, const int* in_sizes, int n_in,
                              void* d_out, int out_size, void* d_ws, size_t ws_size,
                              hipStream_t stream) {
    const float* x  = (const float*)d_in[0];
    const float* Wq = (const float*)d_in[1];
    const float* bq = (const float*)d_in[2];
    const float* Wk = (const float*)d_in[3];
    const float* bk = (const float*)d_in[4];
    const float* Wv = (const float*)d_in[5];
    const float* bv = (const float*)d_in[6];
    const float* Wo = (const float*)d_in[7];
    const float* bo = (const float*)d_in[8];
    const float* ls = (const float*)d_in[9];
    const float* w1 = (const float*)d_in[10];
    const float* b1 = (const float*)d_in[11];
    const float* w2 = (const float*)d_in[12];

    char* ws = (char*)d_ws;
    short* wqkv_f = (short*)(ws + 0);           //   393,216 B
    short* wo_f   = (short*)(ws + 393216);      //   131,072 B
    float* bias8  = (float*)(ws + 524288);      //   131,072 B
    float* scale  = (float*)(ws + 655360);      //        32 B
    float* b225g  = (float*)(ws + 786432);      //     7,200 B
    float* out    = (float*)d_out;

    hipLaunchKernelGGL(wtrans, dim3(128), dim3(256), 0, stream, Wq, Wk, Wv, Wo, wqkv_f, wo_f);
    hipLaunchKernelGGL(bias_mlp, dim3(225), dim3(256), 0, stream, ls, w1, b1, w2, b225g, scale);
    hipLaunchKernelGGL(bias_expand, dim3(128), dim3(256), 0, stream, b225g, bias8);
    hipLaunchKernelGGL(swin_fused, dim3(1024), dim3(512), 0, stream,
                       x, wqkv_f, wo_f, bq, bk, bv, bo, bias8, scale, out);
}

// Round 12
// 214.145 us; speedup vs baseline: 1.5954x; 1.0229x over previous
//
#include <hip/hip_runtime.h>
#include <hip/hip_bf16.h>

typedef float floatx4 __attribute__((ext_vector_type(4)));
typedef short shortx8 __attribute__((ext_vector_type(8)));
typedef short shortx4 __attribute__((ext_vector_type(4)));

#define CFENCE() asm volatile("" ::: "memory")

__device__ __forceinline__ float bf2f(short s) {
    union { unsigned u; float f; } cv;
    cv.u = ((unsigned)(unsigned short)s) << 16;
    return cv.f;
}
__device__ __forceinline__ short f2bf(float f) {
    union { float f; unsigned u; } cv; cv.f = f;
    unsigned r = (cv.u + 0x7fffu + ((cv.u >> 16) & 1u)) >> 16;
    return (short)r;
}

// ---------------- K0a: weights -> bf16 fragment-major layout ----------------
__global__ __launch_bounds__(256) void wtrans(const float* __restrict__ Wq,
                                              const float* __restrict__ Wk,
                                              const float* __restrict__ Wv,
                                              const float* __restrict__ Wo,
                                              short* __restrict__ wqkv_f,
                                              short* __restrict__ wo_f) {
    int gtid = blockIdx.x * 256 + threadIdx.x;
    int f = gtid >> 6, lane = gtid & 63;
    int quad = lane >> 4, l15 = lane & 15;
    if (f < 384) {
        int n16 = f >> 3, kt = f & 7;
        int n = n16 * 16 + l15, z = n >> 8, ncol = n & 255;
        const float* src = (z == 0) ? Wq : (z == 1) ? Wk : Wv;
        shortx8 s;
#pragma unroll
        for (int j = 0; j < 8; ++j)
            s[j] = f2bf(src[(size_t)(kt * 32 + quad * 8 + j) * 256 + ncol]);
        *(shortx8*)(wqkv_f + (size_t)f * 512 + lane * 8) = s;
    } else {
        int f2 = f - 384;
        int n16 = f2 >> 3, kt = f2 & 7;
        int n = n16 * 16 + l15;
        shortx8 s;
#pragma unroll
        for (int j = 0; j < 8; ++j)
            s[j] = f2bf(Wo[(size_t)(kt * 32 + quad * 8 + j) * 256 + n]);
        *(shortx8*)(wo_f + (size_t)f2 * 512 + lane * 8) = s;
    }
}

// ---------------- K0b: CPB MLP ----------------
__device__ __forceinline__ float sgnlog(float x) {
    return copysignf(__log2f(fabsf(x) + 1.f) / 3.f, x);
}
__global__ __launch_bounds__(256) void bias_mlp(const float* __restrict__ ls,
                                                const float* __restrict__ w1,
                                                const float* __restrict__ b1,
                                                const float* __restrict__ w2,
                                                float* __restrict__ b225g,
                                                float* __restrict__ scaleOut) {
    int e = blockIdx.x;
    int tid = threadIdx.x, lane = tid & 63, wid = tid >> 6;
    if (e == 0 && tid < 8) scaleOut[tid] = expf(fminf(ls[tid], 4.6051701859880914f));
    int dh = e / 15 - 7, dw = e % 15 - 7;
    float t0 = sgnlog(8.f * (float)dh / 7.f);
    float t1 = sgnlog(8.f * (float)dw / 7.f);
    float acc[8];
#pragma unroll
    for (int j = 0; j < 8; ++j) acc[j] = 0.f;
#pragma unroll
    for (int s = 0; s < 2; ++s) {
        int hsm = tid + s * 256;
        float hid = fmaxf(0.f, t0 * w1[hsm] + t1 * w1[512 + hsm] + b1[hsm]);
#pragma unroll
        for (int j = 0; j < 8; ++j) acc[j] += hid * w2[hsm * 8 + j];
    }
#pragma unroll
    for (int off = 1; off < 64; off <<= 1)
#pragma unroll
        for (int j = 0; j < 8; ++j) acc[j] += __shfl_xor(acc[j], off, 64);
    __shared__ float red[4][8];
    if (lane == 0)
#pragma unroll
        for (int j = 0; j < 8; ++j) red[wid][j] = acc[j];
    __syncthreads();
    if (tid < 8)
        b225g[e * 8 + tid] = red[0][tid] + red[1][tid] + red[2][tid] + red[3][tid];
}

// ---------------- K0c: expand to per-head 64x64 bias, [h][i][j] (i=query row) ----------
__global__ __launch_bounds__(256) void bias_expand(const float* __restrict__ b225g,
                                                   float* __restrict__ bias8) {
    int f = blockIdx.x * 256 + threadIdx.x;
    int h = f >> 12, ij = f & 4095, i = ij >> 6, j = ij & 63;
    int dh = (i >> 3) - (j >> 3), dw = (i & 7) - (j & 7);
    int e = (dh + 7) * 15 + (dw + 7);
    float v = b225g[e * 8 + h];
    bias8[f] = 16.f / (1.f + expf(-v));
}

// token row -> pixel (roll by +4 both ways, same map fwd/bwd)
__device__ __forceinline__ int row2pix(int row) {
    int w = row >> 6, t = row & 63;
    int b = w >> 6, wi = (w >> 3) & 7, wj = w & 7;
    int hh = (wi * 8 + (t >> 3) + 4) & 63;
    int ww = (wj * 8 + (t & 7) + 4) & 63;
    return (b * 64 + hh) * 64 + ww;
}

__device__ __forceinline__ int regid(int t, int wi, int wj) {
    int a = (wi < 7) ? 0 : (((t >> 3) < 4) ? 1 : 2);
    int b = (wj < 7) ? 0 : (((t & 7) < 4) ? 1 : 2);
    return a * 3 + b;
}

// ---------------- Fused: QKV + attention + O-proj, one 512-thread block per window ----
// r11 skeleton + round-12 delta: MANUAL 2-deep double-buffer on every global fragment
// load (weights in QKV, bw in O-proj). r11 showed the compiler stops at 96 VGPR and does
// not pipeline VMEM across the MFMA bursts — load->use distance was ~0, so each kt
// iteration ate a full L2 latency with only 2 waves/SIMD to hide it. Now kt+1's loads
// issue before kt's MFMA burst (~240 issue-cycles of cover). All buffer indices are
// compile-time constants under full unroll (no scratch, rule #20).
__global__ __launch_bounds__(512) void swin_fused(const float* __restrict__ x,
                                                  const short* __restrict__ wf,
                                                  const short* __restrict__ wof,
                                                  const float* __restrict__ bq,
                                                  const float* __restrict__ bk_,
                                                  const float* __restrict__ bv,
                                                  const float* __restrict__ bo,
                                                  const float* __restrict__ bias8,
                                                  const float* __restrict__ scale,
                                                  float* __restrict__ out) {
    __shared__ __align__(16) short lds[68608];   // 137216 B
    int tid = threadIdx.x, lane = tid & 63, wid = tid >> 6;   // wid 0..7
    int quad = lane >> 4, l15 = lane & 15;
    int win = blockIdx.x;
    int wi = (win >> 3) & 7, wj = win & 7;
    bool need_mask = (wi == 7) || (wj == 7);

    short* xtile = lds;                       // 16384 shorts (32 KB), frag-major+swizzle
    short* qn = &lds[16384 + wid * 6528];     // [64][34]  (2176)
    short* kn = qn + 2176;                    // [64][34]  (2176)
    short* vt = qn + 4352;                    // [32][68]  (2176)
    short* P  = qn;                           // [64][68]  (4352) aliases qn+kn

    // ---- stage x -> xtile (fp32 -> bf16 frag-major, XOR-swizzled slots) ----
    {
        int r = tid >> 3, seg = tid & 7;      // token r, kt-segment seg
        const float* src = x + (size_t)row2pix(win * 64 + r) * 256 + seg * 32;
        short* fbase = &xtile[((r >> 4) * 8 + seg) * 512];
        int slo = (r & 15) ^ seg;             // swizzled low slot bits
#pragma unroll
        for (int c4 = 0; c4 < 4; ++c4) {
            float4 u0 = *(const float4*)(src + c4 * 8);
            float4 u1 = *(const float4*)(src + c4 * 8 + 4);
            shortx8 t;
            t[0] = f2bf(u0.x); t[1] = f2bf(u0.y); t[2] = f2bf(u0.z); t[3] = f2bf(u0.w);
            t[4] = f2bf(u1.x); t[5] = f2bf(u1.y); t[6] = f2bf(u1.z); t[7] = f2bf(u1.w);
            *(shortx8*)(fbase + (c4 * 16 + slo) * 8) = t;
        }
    }
    __syncthreads();

    int h = wid;
    float sc = scale[h];
    const short* wbq = wf + (size_t)(2 * h) * 8 * 512 + lane * 8;          // head's Wq frags
    const short* wbk = wf + (size_t)(16 + 2 * h) * 8 * 512 + lane * 8;     // Wk
    const short* wbv = wf + (size_t)(32 + 2 * h) * 8 * 512 + lane * 8;     // Wv

    // ======== QKV GEMM (C^T, single phase, 2-deep weight prefetch): 24 MFMA/kt ========
    floatx4 aq[2][4], ak[2][4], av[2][4];
#pragma unroll
    for (int i = 0; i < 2; ++i)
#pragma unroll
        for (int mt = 0; mt < 4; ++mt) {
            aq[i][mt] = (floatx4){0.f, 0.f, 0.f, 0.f};
            ak[i][mt] = (floatx4){0.f, 0.f, 0.f, 0.f};
            av[i][mt] = (floatx4){0.f, 0.f, 0.f, 0.f};
        }
    shortx8 wqf[2][2], wkf[2][2], wvf[2][2];   // [buf][i]
#pragma unroll
    for (int i = 0; i < 2; ++i) {              // prologue: kt=0 -> buf 0
        wqf[0][i] = *(const shortx8*)(wbq + (size_t)(i * 8 + 0) * 512);
        wkf[0][i] = *(const shortx8*)(wbk + (size_t)(i * 8 + 0) * 512);
        wvf[0][i] = *(const shortx8*)(wbv + (size_t)(i * 8 + 0) * 512);
    }
#pragma unroll
    for (int kt = 0; kt < 8; ++kt) {
        const int cur = kt & 1, nxt = cur ^ 1;
        if (kt < 7) {
#pragma unroll
            for (int i = 0; i < 2; ++i) {      // issue kt+1 loads before kt's MFMA burst
                wqf[nxt][i] = *(const shortx8*)(wbq + (size_t)(i * 8 + kt + 1) * 512);
                wkf[nxt][i] = *(const shortx8*)(wbk + (size_t)(i * 8 + kt + 1) * 512);
                wvf[nxt][i] = *(const shortx8*)(wbv + (size_t)(i * 8 + kt + 1) * 512);
            }
        }
        shortx8 af[4];
#pragma unroll
        for (int mt = 0; mt < 4; ++mt)
            af[mt] = *(const shortx8*)&xtile[(mt * 8 + kt) * 512 + (lane ^ kt) * 8];
        __builtin_amdgcn_s_setprio(1);
#pragma unroll
        for (int i = 0; i < 2; ++i)
#pragma unroll
            for (int mt = 0; mt < 4; ++mt) {
                aq[i][mt] = __builtin_amdgcn_mfma_f32_16x16x32_bf16(wqf[cur][i], af[mt], aq[i][mt], 0, 0, 0);
                ak[i][mt] = __builtin_amdgcn_mfma_f32_16x16x32_bf16(wkf[cur][i], af[mt], ak[i][mt], 0, 0, 0);
                av[i][mt] = __builtin_amdgcn_mfma_f32_16x16x32_bf16(wvf[cur][i], af[mt], av[i][mt], 0, 0, 0);
            }
        __builtin_amdgcn_s_setprio(0);
    }
    // ---- bias + cosine norms (token = col; sum over quads via shfl) ----
    float qs[4], ks[4];
#pragma unroll
    for (int mt = 0; mt < 4; ++mt) { qs[mt] = 0.f; ks[mt] = 0.f; }
#pragma unroll
    for (int i = 0; i < 2; ++i) {
        float bqv[4], bkv[4], bvv[4];
#pragma unroll
        for (int r = 0; r < 4; ++r) {
            int d = i * 16 + quad * 4 + r;
            bqv[r] = bq[h * 32 + d];
            bkv[r] = bk_[h * 32 + d];
            bvv[r] = bv[h * 32 + d];
        }
#pragma unroll
        for (int mt = 0; mt < 4; ++mt)
#pragma unroll
            for (int r = 0; r < 4; ++r) {
                float qv = aq[i][mt][r] + bqv[r]; aq[i][mt][r] = qv; qs[mt] += qv * qv;
                float kv = ak[i][mt][r] + bkv[r]; ak[i][mt][r] = kv; ks[mt] += kv * kv;
                av[i][mt][r] += bvv[r];
            }
    }
#pragma unroll
    for (int mt = 0; mt < 4; ++mt) {
        qs[mt] += __shfl_xor(qs[mt], 16, 64); qs[mt] += __shfl_xor(qs[mt], 32, 64);
        ks[mt] += __shfl_xor(ks[mt], 16, 64); ks[mt] += __shfl_xor(ks[mt], 32, 64);
    }
    CFENCE();
    // ---- write normalized q,k and transposed v into LDS ----
#pragma unroll
    for (int mt = 0; mt < 4; ++mt) {
        float qr = sc / fmaxf(sqrtf(qs[mt]), 1e-12f);
        float kr = 1.f / fmaxf(sqrtf(ks[mt]), 1e-12f);
        int tok = mt * 16 + l15;
#pragma unroll
        for (int i = 0; i < 2; ++i) {
            shortx4 oq, ok;
#pragma unroll
            for (int r = 0; r < 4; ++r) {
                oq[r] = f2bf(aq[i][mt][r] * qr);
                ok[r] = f2bf(ak[i][mt][r] * kr);
            }
            *(shortx4*)&qn[tok * 34 + i * 16 + quad * 4] = oq;
            *(shortx4*)&kn[tok * 34 + i * 16 + quad * 4] = ok;
#pragma unroll
            for (int r = 0; r < 4; ++r)
                vt[(i * 16 + quad * 4 + r) * 68 + tok] = f2bf(av[i][mt][r]);
        }
    }
    CFENCE();
    // ======== QK^T, swapped: S^T[ktok][qtok] = mfma(K-frag, Q-frag) ========
    shortx8 aqf[4], bkf[4];
#pragma unroll
    for (int mt = 0; mt < 4; ++mt)
        aqf[mt] = *(const shortx8*)&qn[(mt * 16 + l15) * 34 + quad * 8];
#pragma unroll
    for (int nt = 0; nt < 4; ++nt)
        bkf[nt] = *(const shortx8*)&kn[(nt * 16 + l15) * 34 + quad * 8];
    floatx4 S[4][4];   // S[mt][nt]: rows ktok = mt*16+quad*4+reg, cols qtok = nt*16+l15
#pragma unroll
    for (int mt = 0; mt < 4; ++mt)
#pragma unroll
        for (int nt = 0; nt < 4; ++nt) {
            floatx4 z = {0.f, 0.f, 0.f, 0.f};
            S[mt][nt] = __builtin_amdgcn_mfma_f32_16x16x32_bf16(bkf[mt], aqf[nt], z, 0, 0, 0);
        }
    // ======== softmax over ktok (in-thread + 2 shfls per qtok) ========
    const float* bh = bias8 + (h << 12);
    float bound = sc + 16.5f;
    int jd[4][4];
    if (need_mask) {
#pragma unroll
        for (int mt = 0; mt < 4; ++mt)
#pragma unroll
            for (int reg = 0; reg < 4; ++reg)
                jd[mt][reg] = regid(mt * 16 + quad * 4 + reg, wi, wj);
    }
    float rsinv[4];
#pragma unroll
    for (int nt = 0; nt < 4; ++nt) {
        int qt = nt * 16 + l15;
        int iid = need_mask ? regid(qt, wi, wj) : 0;
        const float* brow = bh + qt * 64;
        float rowsum = 0.f;
#pragma unroll
        for (int mt = 0; mt < 4; ++mt) {
            float4 b4 = *(const float4*)&brow[mt * 16 + quad * 4];
#pragma unroll
            for (int reg = 0; reg < 4; ++reg) {
                float bb = (reg == 0) ? b4.x : (reg == 1) ? b4.y : (reg == 2) ? b4.z : b4.w;
                float v = S[mt][nt][reg] + bb;
                if (need_mask && iid != jd[mt][reg]) v -= 100.f;
                float pe = __expf(v - bound);
                S[mt][nt][reg] = pe;
                rowsum += pe;
            }
        }
        rowsum += __shfl_xor(rowsum, 16, 64);
        rowsum += __shfl_xor(rowsum, 32, 64);
        rsinv[nt] = 1.f / rowsum;
    }
    CFENCE();
    // ---- P into LDS (qtok-major, normalization folded in; 16 shortx4 writes) ----
#pragma unroll
    for (int nt = 0; nt < 4; ++nt)
#pragma unroll
        for (int mt = 0; mt < 4; ++mt) {
            shortx4 s;
#pragma unroll
            for (int reg = 0; reg < 4; ++reg)
                s[reg] = f2bf(S[mt][nt][reg] * rsinv[nt]);
            *(shortx4*)&P[(nt * 16 + l15) * 68 + mt * 16 + quad * 4] = s;
        }
    CFENCE();
    // ======== PV (P pre-normalized) ========
    floatx4 O[4][2];
#pragma unroll
    for (int mt = 0; mt < 4; ++mt)
#pragma unroll
        for (int nt = 0; nt < 2; ++nt) O[mt][nt] = (floatx4){0.f, 0.f, 0.f, 0.f};
#pragma unroll
    for (int ks2 = 0; ks2 < 2; ++ks2) {
        shortx8 pa[4], vb[2];
#pragma unroll
        for (int mt = 0; mt < 4; ++mt)
            pa[mt] = *(const shortx8*)&P[(mt * 16 + l15) * 68 + ks2 * 32 + quad * 8];
#pragma unroll
        for (int nt = 0; nt < 2; ++nt)
            vb[nt] = *(const shortx8*)&vt[(nt * 16 + l15) * 68 + ks2 * 32 + quad * 8];
#pragma unroll
        for (int mt = 0; mt < 4; ++mt)
#pragma unroll
            for (int nt = 0; nt < 2; ++nt)
                O[mt][nt] = __builtin_amdgcn_mfma_f32_16x16x32_bf16(pa[mt], vb[nt], O[mt][nt], 0, 0, 0);
    }
    // ---- pack to bf16 (already normalized) ----
    shortx4 Obf[4][2];
#pragma unroll
    for (int mt = 0; mt < 4; ++mt)
#pragma unroll
        for (int nt = 0; nt < 2; ++nt) {
            shortx4 s;
#pragma unroll
            for (int reg = 0; reg < 4; ++reg)
                s[reg] = f2bf(O[mt][nt][reg]);
            Obf[mt][nt] = s;
        }

    // ---- all waves done: xtile + scratch dead; gather Ao[64][264], O-proj ----
    __syncthreads();
    short* Ao = lds;
#pragma unroll
    for (int mt = 0; mt < 4; ++mt)
#pragma unroll
        for (int nt = 0; nt < 2; ++nt)
#pragma unroll
            for (int reg = 0; reg < 4; ++reg)
                Ao[(mt * 16 + quad * 4 + reg) * 264 + h * 32 + nt * 16 + l15] =
                    Obf[mt][nt][reg];
    __syncthreads();

    int pix[4];
#pragma unroll
    for (int mt = 0; mt < 4; ++mt) pix[mt] = row2pix(win * 64 + mt * 16 + l15);

    const short* wbo = wof + (size_t)(wid * 2) * 8 * 512 + lane * 8;

    floatx4 acc2[2][4];   // [nt][mt], wave covers n16 = wid*2 + nt
#pragma unroll
    for (int nt = 0; nt < 2; ++nt)
#pragma unroll
        for (int mt = 0; mt < 4; ++mt) acc2[nt][mt] = (floatx4){0.f, 0.f, 0.f, 0.f};
    shortx8 bw[2][2];      // [buf][nt]
#pragma unroll
    for (int nt = 0; nt < 2; ++nt)
        bw[0][nt] = *(const shortx8*)(wbo + (size_t)(nt * 8 + 0) * 512);
#pragma unroll
    for (int kt = 0; kt < 8; ++kt) {
        const int cur = kt & 1, nxt = cur ^ 1;
        if (kt < 7) {
#pragma unroll
            for (int nt = 0; nt < 2; ++nt)
                bw[nxt][nt] = *(const shortx8*)(wbo + (size_t)(nt * 8 + kt + 1) * 512);
        }
        shortx8 af2[4];
#pragma unroll
        for (int mt = 0; mt < 4; ++mt)
            af2[mt] = *(const shortx8*)&Ao[(mt * 16 + l15) * 264 + kt * 32 + quad * 8];
        __builtin_amdgcn_s_setprio(1);
#pragma unroll
        for (int nt = 0; nt < 2; ++nt)
#pragma unroll
            for (int mt = 0; mt < 4; ++mt)
                acc2[nt][mt] = __builtin_amdgcn_mfma_f32_16x16x32_bf16(bw[cur][nt], af2[mt], acc2[nt][mt], 0, 0, 0);
        __builtin_amdgcn_s_setprio(0);
    }
#pragma unroll
    for (int nt = 0; nt < 2; ++nt) {
        int nb = (wid * 2 + nt) * 16 + quad * 4;
        float bs[4];
#pragma unroll
        for (int reg = 0; reg < 4; ++reg) bs[reg] = bo[nb + reg];
#pragma unroll
        for (int mt = 0; mt < 4; ++mt) {
            float4 o;
            o.x = acc2[nt][mt][0] + bs[0];
            o.y = acc2[nt][mt][1] + bs[1];
            o.z = acc2[nt][mt][2] + bs[2];
            o.w = acc2[nt][mt][3] + bs[3];
            *(float4*)(out + (size_t)pix[mt] * 256 + nb) = o;
        }
    }
}

// ---------------- launch ----------------
extern "C" void kernel_launch(void* const* d_in, const int* in_sizes, int n_in,
                              void* d_out, int out_size, void* d_ws, size_t ws_size,
                              hipStream_t stream) {
    const float* x  = (const float*)d_in[0];
    const float* Wq = (const float*)d_in[1];
    const float* bq = (const float*)d_in[2];
    const float* Wk = (const float*)d_in[3];
    const float* bk = (const float*)d_in[4];
    const float* Wv = (const float*)d_in[5];
    const float* bv = (const float*)d_in[6];
    const float* Wo = (const float*)d_in[7];
    const float* bo = (const float*)d_in[8];
    const float* ls = (const float*)d_in[9];
    const float* w1 = (const float*)d_in[10];
    const float* b1 = (const float*)d_in[11];
    const float* w2 = (const float*)d_in[12];

    char* ws = (char*)d_ws;
    short* wqkv_f = (short*)(ws + 0);           //   393,216 B
    short* wo_f   = (short*)(ws + 393216);      //   131,072 B
    float* bias8  = (float*)(ws + 524288);      //   131,072 B
    float* scale  = (float*)(ws + 655360);      //        32 B
    float* b225g  = (float*)(ws + 786432);      //     7,200 B
    float* out    = (float*)d_out;

    hipLaunchKernelGGL(wtrans, dim3(128), dim3(256), 0, stream, Wq, Wk, Wv, Wo, wqkv_f, wo_f);
    hipLaunchKernelGGL(bias_mlp, dim3(225), dim3(256), 0, stream, ls, w1, b1, w2, b225g, scale);
    hipLaunchKernelGGL(bias_expand, dim3(128), dim3(256), 0, stream, b225g, bias8);
    hipLaunchKernelGGL(swin_fused, dim3(1024), dim3(512), 0, stream,
                       x, wqkv_f, wo_f, bq, bk, bv, bo, bias8, scale, out);
}